// Round 4
// baseline (440.379 us; speedup 1.0000x reference)
//
#include <hip/hip_runtime.h>
#include <hip/hip_bf16.h>

#define BATCH 2
#define SEQ   2048
#define HID   2048
#define NH    16
#define NKV   8
#define HD    128

typedef __bf16 bf16;
typedef bf16  bf16x8  __attribute__((ext_vector_type(8)));
typedef bf16  bf16x4  __attribute__((ext_vector_type(4)));
typedef float floatx4 __attribute__((ext_vector_type(4)));

typedef __attribute__((address_space(3))) void lds_void;
typedef const __attribute__((address_space(1))) void gmem_void;

__device__ inline void async16(const void* g, void* l) {
    __builtin_amdgcn_global_load_lds((gmem_void*)g, (lds_void*)l, 16, 0, 0);
}

// workspace layout constants (elements)
#define XN  8388608u
#define QWN 4194304u
#define KWN 2097152u
#define VWN 2097152u
#define OWN 4194304u

// ---------------------------------------------------------------------------
// Fused f32 -> bf16 convert for x + all four weights in ONE launch.
// ---------------------------------------------------------------------------
__global__ __launch_bounds__(256) void cvt_all(bf16* __restrict__ dst,
                                               const float* __restrict__ x,
                                               const float* __restrict__ qw,
                                               const float* __restrict__ kw,
                                               const float* __restrict__ vw,
                                               const float* __restrict__ ow)
{
    const int blk = blockIdx.x;
    const float* src;
    size_t off;
    if (blk < 4096)      { src = x;  off = (size_t)blk * 2048; }
    else if (blk < 6144) { src = qw; off = (size_t)(blk - 4096) * 2048; }
    else if (blk < 7168) { src = kw; off = (size_t)(blk - 6144) * 2048; }
    else if (blk < 8192) { src = vw; off = (size_t)(blk - 7168) * 2048; }
    else                 { src = ow; off = (size_t)(blk - 8192) * 2048; }

    const int t = threadIdx.x * 8;
    const float4* p = (const float4*)(src + off + t);
    float4 u0 = p[0], u1 = p[1];
    bf16x8 v;
    v[0] = (bf16)u0.x; v[1] = (bf16)u0.y; v[2] = (bf16)u0.z; v[3] = (bf16)u0.w;
    v[4] = (bf16)u1.x; v[5] = (bf16)u1.y; v[6] = (bf16)u1.z; v[7] = (bf16)u1.w;
    *(bf16x8*)(dst + (size_t)blk * 2048 + t) = v;
}

// ---------------------------------------------------------------------------
// GEMM  C = A[M,K] * W[N,K]^T, 128x128 tile, BK=64.
// ---------------------------------------------------------------------------
template <int AMODE, int WMODE, int CMODE>
__global__ __launch_bounds__(256) void gemm128(void* __restrict__ Cp,
                                               const void* __restrict__ Ap,
                                               const void* __restrict__ Wp,
                                               int M, int N, int K)
{
    __shared__ bf16 As[128 * 64];
    __shared__ bf16 Ws[128 * 64];

    const int tid  = threadIdx.x;
    const int wv   = tid >> 6;
    const int lane = tid & 63;
    const int quad = lane >> 4;
    const int c    = lane & 15;

    const int m0 = blockIdx.x * 128;
    const int n0 = blockIdx.y * 128;
    const int wm = (wv >> 1) * 64;
    const int wn = (wv & 1) * 64;

    const int arow = lane >> 3;
    const int acol = (lane & 7) * 8;

    floatx4 acc[4][4] = {};

    for (int k0 = 0; k0 < K; k0 += 64) {
        if constexpr (AMODE == 0) {
            const float* A = (const float*)Ap;
            #pragma unroll
            for (int it = 0; it < 4; it++) {
                int row = it * 32 + (tid >> 3);
                int col = (tid & 7) * 8;
                const float4* p = (const float4*)(A + (size_t)(m0 + row) * K + k0 + col);
                float4 u0 = p[0], u1 = p[1];
                bf16x8 v;
                v[0] = (bf16)u0.x; v[1] = (bf16)u0.y; v[2] = (bf16)u0.z; v[3] = (bf16)u0.w;
                v[4] = (bf16)u1.x; v[5] = (bf16)u1.y; v[6] = (bf16)u1.z; v[7] = (bf16)u1.w;
                *(bf16x8*)(&As[row * 64 + col]) = v;
            }
        } else {
            const bf16* A = (const bf16*)Ap;
            #pragma unroll
            for (int ch = 0; ch < 4; ch++) {
                int row = wv * 32 + ch * 8 + arow;
                async16(A + (size_t)(m0 + row) * K + k0 + acol,
                        &As[(wv * 32 + ch * 8) * 64]);
            }
        }
        if constexpr (WMODE == 0) {
            const float* W = (const float*)Wp;
            #pragma unroll
            for (int it = 0; it < 4; it++) {
                int row = it * 32 + (tid >> 3);
                int col = (tid & 7) * 8;
                const float4* p = (const float4*)(W + (size_t)(n0 + row) * K + k0 + col);
                float4 u0 = p[0], u1 = p[1];
                bf16x8 v;
                v[0] = (bf16)u0.x; v[1] = (bf16)u0.y; v[2] = (bf16)u0.z; v[3] = (bf16)u0.w;
                v[4] = (bf16)u1.x; v[5] = (bf16)u1.y; v[6] = (bf16)u1.z; v[7] = (bf16)u1.w;
                *(bf16x8*)(&Ws[row * 64 + col]) = v;
            }
        } else {
            const bf16* W = (const bf16*)Wp;
            #pragma unroll
            for (int ch = 0; ch < 4; ch++) {
                int row = wv * 32 + ch * 8 + arow;
                async16(W + (size_t)(n0 + row) * K + k0 + acol,
                        &Ws[(wv * 32 + ch * 8) * 64]);
            }
        }
        __syncthreads();

        #pragma unroll
        for (int t = 0; t < 2; t++) {
            bf16x8 af[4], bw[4];
            #pragma unroll
            for (int i = 0; i < 4; i++)
                af[i] = *(const bf16x8*)(&As[(wm + i * 16 + c) * 64 + t * 32 + quad * 8]);
            #pragma unroll
            for (int j = 0; j < 4; j++)
                bw[j] = *(const bf16x8*)(&Ws[(wn + j * 16 + c) * 64 + t * 32 + quad * 8]);
            #pragma unroll
            for (int i = 0; i < 4; i++)
                #pragma unroll
                for (int j = 0; j < 4; j++)
                    acc[i][j] = __builtin_amdgcn_mfma_f32_16x16x32_bf16(af[i], bw[j], acc[i][j], 0, 0, 0);
        }
        __syncthreads();
    }

    if constexpr (CMODE == 0) {
        float* C = (float*)Cp;
        #pragma unroll
        for (int i = 0; i < 4; i++)
            #pragma unroll
            for (int j = 0; j < 4; j++)
                #pragma unroll
                for (int r = 0; r < 4; r++) {
                    int m = m0 + wm + i * 16 + quad * 4 + r;
                    int n = n0 + wn + j * 16 + c;
                    C[(size_t)m * N + n] = acc[i][j][r];
                }
    } else if constexpr (CMODE == 1) {
        bf16* C = (bf16*)Cp;
        #pragma unroll
        for (int i = 0; i < 4; i++)
            #pragma unroll
            for (int j = 0; j < 4; j++)
                #pragma unroll
                for (int r = 0; r < 4; r++) {
                    int m = m0 + wm + i * 16 + quad * 4 + r;
                    int n = n0 + wn + j * 16 + c;
                    C[(size_t)m * N + n] = (bf16)acc[i][j][r];
                }
    } else if constexpr (CMODE == 2) {
        bf16* C = (bf16*)Cp;
        const int b = m0 >> 11;
        #pragma unroll
        for (int j = 0; j < 4; j++) {
            int n = n0 + wn + j * 16 + c;
            size_t base = ((size_t)b * N + n) * 2048;
            #pragma unroll
            for (int i = 0; i < 4; i++) {
                int s0 = (m0 & 2047) + wm + i * 16 + quad * 4;
                bf16x4 v;
                #pragma unroll
                for (int r = 0; r < 4; r++) v[r] = (bf16)acc[i][j][r];
                *(bf16x4*)(&C[base + s0]) = v;
            }
        }
    } else {
        bf16* Cq = (bf16*)Cp;
        if (n0 < 2048) {
            #pragma unroll
            for (int i = 0; i < 4; i++)
                #pragma unroll
                for (int j = 0; j < 4; j++)
                    #pragma unroll
                    for (int r = 0; r < 4; r++) {
                        int m = m0 + wm + i * 16 + quad * 4 + r;
                        int n = n0 + wn + j * 16 + c;
                        Cq[(size_t)m * 2048 + n] = (bf16)acc[i][j][r];
                    }
        } else if (n0 < 3072) {
            bf16* Ck = Cq + XN;
            #pragma unroll
            for (int i = 0; i < 4; i++)
                #pragma unroll
                for (int j = 0; j < 4; j++)
                    #pragma unroll
                    for (int r = 0; r < 4; r++) {
                        int m = m0 + wm + i * 16 + quad * 4 + r;
                        int n = n0 - 2048 + wn + j * 16 + c;
                        Ck[(size_t)m * 1024 + n] = (bf16)acc[i][j][r];
                    }
        } else {
            bf16* Cv = Cq + XN + QWN;
            const int b = m0 >> 11;
            #pragma unroll
            for (int j = 0; j < 4; j++) {
                int n = n0 - 3072 + wn + j * 16 + c;
                size_t base = ((size_t)b * 1024 + n) * 2048;
                #pragma unroll
                for (int i = 0; i < 4; i++) {
                    int s0 = (m0 & 2047) + wm + i * 16 + quad * 4;
                    bf16x4 v;
                    #pragma unroll
                    for (int r = 0; r < 4; r++) v[r] = (bf16)acc[i][j][r];
                    *(bf16x4*)(&Cv[base + s0]) = v;
                }
            }
        }
    }
}

// ---------------------------------------------------------------------------
// O-projection GEMM: 128x64 tile, BK=64.
// ---------------------------------------------------------------------------
__global__ __launch_bounds__(256) void gemm_o64(float* __restrict__ C,
                                                const bf16* __restrict__ A,
                                                const bf16* __restrict__ W,
                                                int M, int N, int K)
{
    __shared__ bf16 As[128 * 64];
    __shared__ bf16 Ws[64 * 64];

    const int tid  = threadIdx.x;
    const int wv   = tid >> 6;
    const int lane = tid & 63;
    const int quad = lane >> 4;
    const int c    = lane & 15;

    const int m0 = blockIdx.x * 128;
    const int n0 = blockIdx.y * 64;
    const int wm = (wv >> 1) * 64;
    const int wn = (wv & 1) * 32;

    const int arow = lane >> 3;
    const int acol = (lane & 7) * 8;

    floatx4 acc[4][2] = {};

    for (int k0 = 0; k0 < K; k0 += 64) {
        #pragma unroll
        for (int ch = 0; ch < 4; ch++) {
            int row = wv * 32 + ch * 8 + arow;
            async16(A + (size_t)(m0 + row) * K + k0 + acol,
                    &As[(wv * 32 + ch * 8) * 64]);
        }
        #pragma unroll
        for (int ch = 0; ch < 2; ch++) {
            int row = wv * 16 + ch * 8 + arow;
            async16(W + (size_t)(n0 + row) * K + k0 + acol,
                    &Ws[(wv * 16 + ch * 8) * 64]);
        }
        __syncthreads();

        #pragma unroll
        for (int t = 0; t < 2; t++) {
            bf16x8 af[4], bw[2];
            #pragma unroll
            for (int i = 0; i < 4; i++)
                af[i] = *(const bf16x8*)(&As[(wm + i * 16 + c) * 64 + t * 32 + quad * 8]);
            #pragma unroll
            for (int j = 0; j < 2; j++)
                bw[j] = *(const bf16x8*)(&Ws[(wn + j * 16 + c) * 64 + t * 32 + quad * 8]);
            #pragma unroll
            for (int i = 0; i < 4; i++)
                #pragma unroll
                for (int j = 0; j < 2; j++)
                    acc[i][j] = __builtin_amdgcn_mfma_f32_16x16x32_bf16(af[i], bw[j], acc[i][j], 0, 0, 0);
        }
        __syncthreads();
    }

    #pragma unroll
    for (int i = 0; i < 4; i++)
        #pragma unroll
        for (int j = 0; j < 2; j++)
            #pragma unroll
            for (int r = 0; r < 4; r++) {
                int m = m0 + wm + i * 16 + quad * 4 + r;
                int n = n0 + wn + j * 16 + c;
                C[(size_t)m * N + n] = acc[i][j][r];
            }
}

// ---------------------------------------------------------------------------
// RMSNorm(D=128) + RoPE for K ONLY.
// ---------------------------------------------------------------------------
__global__ __launch_bounds__(128) void norm_rope_k(bf16* __restrict__ k,
                                                   const float* __restrict__ pe,
                                                   const float* __restrict__ knw)
{
    const int s  = blockIdx.x;
    const int hh = blockIdx.y;
    const int b  = blockIdx.z;
    const int d  = threadIdx.x;

    bf16* buf = k + (size_t)(b * SEQ + s) * 1024 + hh * HD;

    float x = (float)buf[d];
    float ss = x * x;
    #pragma unroll
    for (int m = 32; m; m >>= 1) ss += __shfl_xor(ss, m);

    __shared__ float red[2];
    __shared__ float nv[128];
    if ((d & 63) == 0) red[d >> 6] = ss;
    __syncthreads();
    float var = (red[0] + red[1]) * (1.0f / 128.0f);
    float nx = x * rsqrtf(var + 1e-6f) * knw[d];
    nv[d] = nx;
    __syncthreads();

    const float* pev = pe + ((size_t)b * SEQ + s) * HD;
    float o;
    if (d < 64) {
        o = nx * pev[d] - nv[d + 64] * pev[64 + d];
    } else {
        o = nv[d - 64] * pev[d] + nx * pev[d - 64];
    }
    buf[d] = (bf16)o;
}

// ---------------------------------------------------------------------------
// Flash attention, causal, GQA rep=2.
// 128 q rows per block, wave owns 32 (two 16-row groups ib=0,1) -> each
// kf/vf ds_read feeds 2 MFMAs.  64-key tiles, static-max softmax, register
// prefetch across the barrier, P round-trip through per-wave LDS (verified
// round-0 structure).  Causal mask applies on the last TWO tiles.
// P stride 76: quad write-stride hits bank groups {0,24,16,8} -> 2-way max.
// ---------------------------------------------------------------------------
__global__ __launch_bounds__(256) void fattn(bf16* __restrict__ O,
                                             const bf16* __restrict__ Q,
                                             const bf16* __restrict__ Kh,
                                             const bf16* __restrict__ Vtg,
                                             const float* __restrict__ pe,
                                             const float* __restrict__ qnw)
{
    const int h    = blockIdx.y;
    const int b    = blockIdx.z;
    const int qblk = (h & 8) ? (int)blockIdx.x
                             : ((int)gridDim.x - 1 - (int)blockIdx.x);
    const int kv   = h >> 1;

    const int tid  = threadIdx.x;
    const int wv   = tid >> 6;
    const int lane = tid & 63;
    const int quad = lane >> 4;
    const int c    = lane & 15;

    __shared__ bf16 Ks[64 * 136];        // [key][d]
    __shared__ bf16 Vs[128 * 72];        // [d][key]
    __shared__ bf16 Ps[4 * 32 * 76];     // per-wave P tile (32 q rows x 64 keys)

    const int qw = qblk * 128 + wv * 32;

    // ---- prologue: load raw q rows (2 groups of 16), RMSNorm + RoPE ----
    bf16x8 qf[2][4];
    #pragma unroll
    for (int ib = 0; ib < 2; ib++) {
        const bf16* qp = Q + (size_t)(b * SEQ + qw + ib * 16 + c) * 2048 + h * HD + quad * 8;
        float qv[4][8];
        float ss = 0.0f;
        #pragma unroll
        for (int t = 0; t < 4; t++) {
            bf16x8 raw = *(const bf16x8*)(qp + t * 32);
            #pragma unroll
            for (int j = 0; j < 8; j++) { qv[t][j] = (float)raw[j]; ss += qv[t][j] * qv[t][j]; }
        }
        ss += __shfl_xor(ss, 16);
        ss += __shfl_xor(ss, 32);
        const float inv = rsqrtf(ss * (1.0f / 128.0f) + 1e-6f);
        const float* pev = pe + (size_t)(b * SEQ + qw + ib * 16 + c) * HD + quad * 8;
        float nx[4][8], pv[4][8];
        #pragma unroll
        for (int t = 0; t < 4; t++)
            #pragma unroll
            for (int j = 0; j < 8; j++) {
                pv[t][j] = pev[t * 32 + j];
                nx[t][j] = qv[t][j] * inv * qnw[t * 32 + quad * 8 + j];
            }
        #pragma unroll
        for (int t = 0; t < 2; t++)
            #pragma unroll
            for (int j = 0; j < 8; j++) {
                qf[ib][t][j]     = (bf16)(nx[t][j] * pv[t][j]     - nx[t + 2][j] * pv[t + 2][j]);
                qf[ib][t + 2][j] = (bf16)(nx[t][j] * pv[t + 2][j] + nx[t + 2][j] * pv[t][j]);
            }
    }

    floatx4 o_acc[2][8] = {};
    float l_part[2][4] = {};

    const bf16* kbase = Kh  + (size_t)b * SEQ * 1024 + kv * HD;        // + s*1024
    const bf16* vbase = Vtg + ((size_t)b * 1024 + kv * HD) * 2048;     // + d*2048

    const int kr  = tid >> 2, ksc = (tid & 3) * 32;   // K staging: 64 rows x 128
    const int vd  = tid >> 1, vkc = (tid & 1) * 32;   // V^T staging: 128 rows x 64
    bf16* psw = &Ps[wv * 32 * 76];
    const int nkt = 2 * qblk + 2;
    const float kS = 0.08838834764831845f * 1.4426950408889634f;  // scale*log2e
    const float kB = 11.5f * 1.4426950408889634f;                 // M*log2e

    // ---- load tile 0 into registers ----
    bf16x8 kreg[4], vreg[4];
    {
        const bf16* kp = kbase + (size_t)kr * 1024 + ksc;
        const bf16* vp = vbase + (size_t)vd * 2048 + vkc;
        #pragma unroll
        for (int i = 0; i < 4; i++) kreg[i] = *(const bf16x8*)(kp + i * 8);
        #pragma unroll
        for (int i = 0; i < 4; i++) vreg[i] = *(const bf16x8*)(vp + i * 8);
    }

    for (int kt = 0; kt < nkt; kt++) {
        const int k0 = kt * 64;
        // ---- commit prefetched tile to LDS ----
        #pragma unroll
        for (int i = 0; i < 4; i++)
            *(bf16x8*)(&Ks[kr * 136 + ksc + i * 8]) = kreg[i];
        #pragma unroll
        for (int i = 0; i < 4; i++)
            *(bf16x8*)(&Vs[vd * 72 + vkc + i * 8]) = vreg[i];
        __syncthreads();

        // ---- prefetch next tile (latency covered by compute below) ----
        if (kt + 1 < nkt) {
            const bf16* kp = kbase + (size_t)(k0 + 64 + kr) * 1024 + ksc;
            const bf16* vp = vbase + (size_t)vd * 2048 + (k0 + 64) + vkc;
            #pragma unroll
            for (int i = 0; i < 4; i++) kreg[i] = *(const bf16x8*)(kp + i * 8);
            #pragma unroll
            for (int i = 0; i < 4; i++) vreg[i] = *(const bf16x8*)(vp + i * 8);
        }

        // ---- QK^T: 32 q-rows x 64 keys (each kf feeds 2 MFMAs) ----
        floatx4 sc0[4] = {}, sc1[4] = {};
        #pragma unroll
        for (int t = 0; t < 4; t++) {
            #pragma unroll
            for (int g = 0; g < 4; g++) {
                bf16x8 kf = *(const bf16x8*)(&Ks[(g * 16 + c) * 136 + t * 32 + quad * 8]);
                sc0[g] = __builtin_amdgcn_mfma_f32_16x16x32_bf16(qf[0][t], kf, sc0[g], 0, 0, 0);
                sc1[g] = __builtin_amdgcn_mfma_f32_16x16x32_bf16(qf[1][t], kf, sc1[g], 0, 0, 0);
            }
        }

        // ---- static-max softmax + P store (row=q, col=key; round-0 layout) ----
        const bool tail = (kt >= nkt - 2);
        #pragma unroll
        for (int r = 0; r < 4; r++) {
            const int qrow0 = qw + quad * 4 + r;
            const int qrow1 = qrow0 + 16;
            #pragma unroll
            for (int g = 0; g < 4; g++) {
                float p0 = exp2f(sc0[g][r] * kS - kB);
                float p1 = exp2f(sc1[g][r] * kS - kB);
                if (tail) {
                    const int key = k0 + g * 16 + c;
                    if (key > qrow0) p0 = 0.0f;
                    if (key > qrow1) p1 = 0.0f;
                }
                l_part[0][r] += p0;
                l_part[1][r] += p1;
                psw[(quad * 4 + r) * 76 + g * 16 + c]        = (bf16)p0;
                psw[(16 + quad * 4 + r) * 76 + g * 16 + c]   = (bf16)p1;
            }
        }
        // drain ds_writes before wave-local ds_reads (vmcnt untouched)
        asm volatile("s_waitcnt lgkmcnt(0)" ::: "memory");
        bf16x8 pf00 = *(const bf16x8*)(&psw[c * 76 + quad * 8]);
        bf16x8 pf01 = *(const bf16x8*)(&psw[c * 76 + 32 + quad * 8]);
        bf16x8 pf10 = *(const bf16x8*)(&psw[(16 + c) * 76 + quad * 8]);
        bf16x8 pf11 = *(const bf16x8*)(&psw[(16 + c) * 76 + 32 + quad * 8]);

        // ---- PV: each vf pair feeds 4 MFMAs ----
        #pragma unroll
        for (int f = 0; f < 8; f++) {
            bf16x8 vf0 = *(const bf16x8*)(&Vs[(f * 16 + c) * 72 + quad * 8]);
            bf16x8 vf1 = *(const bf16x8*)(&Vs[(f * 16 + c) * 72 + 32 + quad * 8]);
            o_acc[0][f] = __builtin_amdgcn_mfma_f32_16x16x32_bf16(pf00, vf0, o_acc[0][f], 0, 0, 0);
            o_acc[0][f] = __builtin_amdgcn_mfma_f32_16x16x32_bf16(pf01, vf1, o_acc[0][f], 0, 0, 0);
            o_acc[1][f] = __builtin_amdgcn_mfma_f32_16x16x32_bf16(pf10, vf0, o_acc[1][f], 0, 0, 0);
            o_acc[1][f] = __builtin_amdgcn_mfma_f32_16x16x32_bf16(pf11, vf1, o_acc[1][f], 0, 0, 0);
        }
        __syncthreads();
    }

    // ---- epilogue: one l-reduction per row, normalize, store ----
    #pragma unroll
    for (int ib = 0; ib < 2; ib++) {
        #pragma unroll
        for (int r = 0; r < 4; r++) {
            float l = l_part[ib][r];
            #pragma unroll
            for (int msk = 8; msk; msk >>= 1) l += __shfl_xor(l, msk);
            const float inv = 1.0f / l;
            bf16* op = O + (size_t)(b * SEQ + qw + ib * 16 + quad * 4 + r) * 2048 + h * HD;
            #pragma unroll
            for (int f = 0; f < 8; f++) op[f * 16 + c] = (bf16)(o_acc[ib][f][r] * inv);
        }
    }
}

// ---------------------------------------------------------------------------
extern "C" void kernel_launch(void* const* d_in, const int* in_sizes, int n_in,
                              void* d_out, int out_size, void* d_ws, size_t ws_size,
                              hipStream_t stream)
{
    const float* x   = (const float*)d_in[0];
    const float* pe  = (const float*)d_in[1];
    const float* qw  = (const float*)d_in[2];
    const float* kw  = (const float*)d_in[3];
    const float* vw  = (const float*)d_in[4];
    const float* ow  = (const float*)d_in[5];
    const float* qnw = (const float*)d_in[6];
    const float* knw = (const float*)d_in[7];
    float* out = (float*)d_out;

    bf16* qb = (bf16*)d_ws;          // [B][S][2048]   row-major (raw q)
    bf16* kb = qb + XN;              // [B][S][1024]   row-major
    bf16* vt = kb + KWN * 2;         // [B][1024][2048] V^T
    bf16* ab = vt + VWN * 2;         // [B][S][2048]   row-major
    bf16* cvt_base = ab + XN;

    const bool fit = ws_size >= (size_t)92274688;
    const int M = BATCH * SEQ;

    if (fit) {
        bf16* xb  = cvt_base;
        bf16* qwb = xb  + XN;
        bf16* owb = qwb + QWN + KWN + VWN;

        cvt_all<<<10240, 256, 0, stream>>>(xb, x, qw, kw, vw, ow);

        gemm128<1, 1, 3><<<dim3(32, 32), 256, 0, stream>>>(qb, xb, qwb, M, 4096, 2048);

        norm_rope_k<<<dim3(SEQ, NKV, BATCH), 128, 0, stream>>>(kb, pe, knw);
        fattn<<<dim3(SEQ / 128, NH, BATCH), 256, 0, stream>>>(ab, qb, kb, vt, pe, qnw);

        gemm_o64<<<dim3(32, 32), 256, 0, stream>>>(out, ab, owb, M, 2048, 2048);
    } else {
        gemm128<0, 0, 1><<<dim3(32, 16), 256, 0, stream>>>(qb, x, qw, M, 2048, 2048);
        gemm128<0, 0, 1><<<dim3(32,  8), 256, 0, stream>>>(kb, x, kw, M, 1024, 2048);
        gemm128<0, 0, 2><<<dim3(32,  8), 256, 0, stream>>>(vt, x, vw, M, 1024, 2048);

        norm_rope_k<<<dim3(SEQ, NKV, BATCH), 128, 0, stream>>>(kb, pe, knw);
        fattn<<<dim3(SEQ / 128, NH, BATCH), 256, 0, stream>>>(ab, qb, kb, vt, pe, qnw);

        gemm128<0, 0, 0><<<dim3(32, 16), 256, 0, stream>>>(out, ab, ow, M, 2048, 2048);
    }
}

// Round 5
// 430.744 us; speedup vs baseline: 1.0224x; 1.0224x over previous
//
#include <hip/hip_runtime.h>
#include <hip/hip_bf16.h>

#define BATCH 2
#define SEQ   2048
#define HID   2048
#define NH    16
#define NKV   8
#define HD    128

typedef __bf16 bf16;
typedef bf16  bf16x8  __attribute__((ext_vector_type(8)));
typedef bf16  bf16x4  __attribute__((ext_vector_type(4)));
typedef float floatx4 __attribute__((ext_vector_type(4)));

typedef __attribute__((address_space(3))) void lds_void;
typedef const __attribute__((address_space(1))) void gmem_void;

__device__ inline void async16(const void* g, void* l) {
    __builtin_amdgcn_global_load_lds((gmem_void*)g, (lds_void*)l, 16, 0, 0);
}

// workspace layout constants (elements)
#define XN  8388608u
#define QWN 4194304u
#define KWN 2097152u
#define VWN 2097152u
#define OWN 4194304u

// ---------------------------------------------------------------------------
// Fused f32 -> bf16 convert for x + all four weights in ONE launch.
// ---------------------------------------------------------------------------
__global__ __launch_bounds__(256) void cvt_all(bf16* __restrict__ dst,
                                               const float* __restrict__ x,
                                               const float* __restrict__ qw,
                                               const float* __restrict__ kw,
                                               const float* __restrict__ vw,
                                               const float* __restrict__ ow)
{
    const int blk = blockIdx.x;
    const float* src;
    size_t off;
    if (blk < 4096)      { src = x;  off = (size_t)blk * 2048; }
    else if (blk < 6144) { src = qw; off = (size_t)(blk - 4096) * 2048; }
    else if (blk < 7168) { src = kw; off = (size_t)(blk - 6144) * 2048; }
    else if (blk < 8192) { src = vw; off = (size_t)(blk - 7168) * 2048; }
    else                 { src = ow; off = (size_t)(blk - 8192) * 2048; }

    const int t = threadIdx.x * 8;
    const float4* p = (const float4*)(src + off + t);
    float4 u0 = p[0], u1 = p[1];
    bf16x8 v;
    v[0] = (bf16)u0.x; v[1] = (bf16)u0.y; v[2] = (bf16)u0.z; v[3] = (bf16)u0.w;
    v[4] = (bf16)u1.x; v[5] = (bf16)u1.y; v[6] = (bf16)u1.z; v[7] = (bf16)u1.w;
    *(bf16x8*)(dst + (size_t)blk * 2048 + t) = v;
}

// ---------------------------------------------------------------------------
// GEMM  C = A[M,K] * W[N,K]^T, 128x128 tile, BK=64.
// ---------------------------------------------------------------------------
template <int AMODE, int WMODE, int CMODE>
__global__ __launch_bounds__(256) void gemm128(void* __restrict__ Cp,
                                               const void* __restrict__ Ap,
                                               const void* __restrict__ Wp,
                                               int M, int N, int K)
{
    __shared__ bf16 As[128 * 64];
    __shared__ bf16 Ws[128 * 64];

    const int tid  = threadIdx.x;
    const int wv   = tid >> 6;
    const int lane = tid & 63;
    const int quad = lane >> 4;
    const int c    = lane & 15;

    const int m0 = blockIdx.x * 128;
    const int n0 = blockIdx.y * 128;
    const int wm = (wv >> 1) * 64;
    const int wn = (wv & 1) * 64;

    const int arow = lane >> 3;
    const int acol = (lane & 7) * 8;

    floatx4 acc[4][4] = {};

    for (int k0 = 0; k0 < K; k0 += 64) {
        if constexpr (AMODE == 0) {
            const float* A = (const float*)Ap;
            #pragma unroll
            for (int it = 0; it < 4; it++) {
                int row = it * 32 + (tid >> 3);
                int col = (tid & 7) * 8;
                const float4* p = (const float4*)(A + (size_t)(m0 + row) * K + k0 + col);
                float4 u0 = p[0], u1 = p[1];
                bf16x8 v;
                v[0] = (bf16)u0.x; v[1] = (bf16)u0.y; v[2] = (bf16)u0.z; v[3] = (bf16)u0.w;
                v[4] = (bf16)u1.x; v[5] = (bf16)u1.y; v[6] = (bf16)u1.z; v[7] = (bf16)u1.w;
                *(bf16x8*)(&As[row * 64 + col]) = v;
            }
        } else {
            const bf16* A = (const bf16*)Ap;
            #pragma unroll
            for (int ch = 0; ch < 4; ch++) {
                int row = wv * 32 + ch * 8 + arow;
                async16(A + (size_t)(m0 + row) * K + k0 + acol,
                        &As[(wv * 32 + ch * 8) * 64]);
            }
        }
        if constexpr (WMODE == 0) {
            const float* W = (const float*)Wp;
            #pragma unroll
            for (int it = 0; it < 4; it++) {
                int row = it * 32 + (tid >> 3);
                int col = (tid & 7) * 8;
                const float4* p = (const float4*)(W + (size_t)(n0 + row) * K + k0 + col);
                float4 u0 = p[0], u1 = p[1];
                bf16x8 v;
                v[0] = (bf16)u0.x; v[1] = (bf16)u0.y; v[2] = (bf16)u0.z; v[3] = (bf16)u0.w;
                v[4] = (bf16)u1.x; v[5] = (bf16)u1.y; v[6] = (bf16)u1.z; v[7] = (bf16)u1.w;
                *(bf16x8*)(&Ws[row * 64 + col]) = v;
            }
        } else {
            const bf16* W = (const bf16*)Wp;
            #pragma unroll
            for (int ch = 0; ch < 4; ch++) {
                int row = wv * 32 + ch * 8 + arow;
                async16(W + (size_t)(n0 + row) * K + k0 + acol,
                        &Ws[(wv * 32 + ch * 8) * 64]);
            }
        }
        __syncthreads();

        #pragma unroll
        for (int t = 0; t < 2; t++) {
            bf16x8 af[4], bw[4];
            #pragma unroll
            for (int i = 0; i < 4; i++)
                af[i] = *(const bf16x8*)(&As[(wm + i * 16 + c) * 64 + t * 32 + quad * 8]);
            #pragma unroll
            for (int j = 0; j < 4; j++)
                bw[j] = *(const bf16x8*)(&Ws[(wn + j * 16 + c) * 64 + t * 32 + quad * 8]);
            #pragma unroll
            for (int i = 0; i < 4; i++)
                #pragma unroll
                for (int j = 0; j < 4; j++)
                    acc[i][j] = __builtin_amdgcn_mfma_f32_16x16x32_bf16(af[i], bw[j], acc[i][j], 0, 0, 0);
        }
        __syncthreads();
    }

    if constexpr (CMODE == 0) {
        float* C = (float*)Cp;
        #pragma unroll
        for (int i = 0; i < 4; i++)
            #pragma unroll
            for (int j = 0; j < 4; j++)
                #pragma unroll
                for (int r = 0; r < 4; r++) {
                    int m = m0 + wm + i * 16 + quad * 4 + r;
                    int n = n0 + wn + j * 16 + c;
                    C[(size_t)m * N + n] = acc[i][j][r];
                }
    } else if constexpr (CMODE == 1) {
        bf16* C = (bf16*)Cp;
        #pragma unroll
        for (int i = 0; i < 4; i++)
            #pragma unroll
            for (int j = 0; j < 4; j++)
                #pragma unroll
                for (int r = 0; r < 4; r++) {
                    int m = m0 + wm + i * 16 + quad * 4 + r;
                    int n = n0 + wn + j * 16 + c;
                    C[(size_t)m * N + n] = (bf16)acc[i][j][r];
                }
    } else if constexpr (CMODE == 2) {
        bf16* C = (bf16*)Cp;
        const int b = m0 >> 11;
        #pragma unroll
        for (int j = 0; j < 4; j++) {
            int n = n0 + wn + j * 16 + c;
            size_t base = ((size_t)b * N + n) * 2048;
            #pragma unroll
            for (int i = 0; i < 4; i++) {
                int s0 = (m0 & 2047) + wm + i * 16 + quad * 4;
                bf16x4 v;
                #pragma unroll
                for (int r = 0; r < 4; r++) v[r] = (bf16)acc[i][j][r];
                *(bf16x4*)(&C[base + s0]) = v;
            }
        }
    } else {
        bf16* Cq = (bf16*)Cp;
        if (n0 < 2048) {
            #pragma unroll
            for (int i = 0; i < 4; i++)
                #pragma unroll
                for (int j = 0; j < 4; j++)
                    #pragma unroll
                    for (int r = 0; r < 4; r++) {
                        int m = m0 + wm + i * 16 + quad * 4 + r;
                        int n = n0 + wn + j * 16 + c;
                        Cq[(size_t)m * 2048 + n] = (bf16)acc[i][j][r];
                    }
        } else if (n0 < 3072) {
            bf16* Ck = Cq + XN;
            #pragma unroll
            for (int i = 0; i < 4; i++)
                #pragma unroll
                for (int j = 0; j < 4; j++)
                    #pragma unroll
                    for (int r = 0; r < 4; r++) {
                        int m = m0 + wm + i * 16 + quad * 4 + r;
                        int n = n0 - 2048 + wn + j * 16 + c;
                        Ck[(size_t)m * 1024 + n] = (bf16)acc[i][j][r];
                    }
        } else {
            bf16* Cv = Cq + XN + QWN;
            const int b = m0 >> 11;
            #pragma unroll
            for (int j = 0; j < 4; j++) {
                int n = n0 - 3072 + wn + j * 16 + c;
                size_t base = ((size_t)b * 1024 + n) * 2048;
                #pragma unroll
                for (int i = 0; i < 4; i++) {
                    int s0 = (m0 & 2047) + wm + i * 16 + quad * 4;
                    bf16x4 v;
                    #pragma unroll
                    for (int r = 0; r < 4; r++) v[r] = (bf16)acc[i][j][r];
                    *(bf16x4*)(&Cv[base + s0]) = v;
                }
            }
        }
    }
}

// ---------------------------------------------------------------------------
// O-projection GEMM: 128x64 tile, BK=64.
// ---------------------------------------------------------------------------
__global__ __launch_bounds__(256) void gemm_o64(float* __restrict__ C,
                                                const bf16* __restrict__ A,
                                                const bf16* __restrict__ W,
                                                int M, int N, int K)
{
    __shared__ bf16 As[128 * 64];
    __shared__ bf16 Ws[64 * 64];

    const int tid  = threadIdx.x;
    const int wv   = tid >> 6;
    const int lane = tid & 63;
    const int quad = lane >> 4;
    const int c    = lane & 15;

    const int m0 = blockIdx.x * 128;
    const int n0 = blockIdx.y * 64;
    const int wm = (wv >> 1) * 64;
    const int wn = (wv & 1) * 32;

    const int arow = lane >> 3;
    const int acol = (lane & 7) * 8;

    floatx4 acc[4][2] = {};

    for (int k0 = 0; k0 < K; k0 += 64) {
        #pragma unroll
        for (int ch = 0; ch < 4; ch++) {
            int row = wv * 32 + ch * 8 + arow;
            async16(A + (size_t)(m0 + row) * K + k0 + acol,
                    &As[(wv * 32 + ch * 8) * 64]);
        }
        #pragma unroll
        for (int ch = 0; ch < 2; ch++) {
            int row = wv * 16 + ch * 8 + arow;
            async16(W + (size_t)(n0 + row) * K + k0 + acol,
                    &Ws[(wv * 16 + ch * 8) * 64]);
        }
        __syncthreads();

        #pragma unroll
        for (int t = 0; t < 2; t++) {
            bf16x8 af[4], bw[2];
            #pragma unroll
            for (int i = 0; i < 4; i++)
                af[i] = *(const bf16x8*)(&As[(wm + i * 16 + c) * 64 + t * 32 + quad * 8]);
            #pragma unroll
            for (int j = 0; j < 2; j++)
                bw[j] = *(const bf16x8*)(&Ws[(wn + j * 16 + c) * 64 + t * 32 + quad * 8]);
            #pragma unroll
            for (int i = 0; i < 4; i++)
                #pragma unroll
                for (int j = 0; j < 2; j++)
                    acc[i][j] = __builtin_amdgcn_mfma_f32_16x16x32_bf16(af[i], bw[j], acc[i][j], 0, 0, 0);
        }
        __syncthreads();
    }

    #pragma unroll
    for (int i = 0; i < 4; i++)
        #pragma unroll
        for (int j = 0; j < 2; j++)
            #pragma unroll
            for (int r = 0; r < 4; r++) {
                int m = m0 + wm + i * 16 + quad * 4 + r;
                int n = n0 + wn + j * 16 + c;
                C[(size_t)m * N + n] = acc[i][j][r];
            }
}

// ---------------------------------------------------------------------------
// RMSNorm(D=128) + RoPE for K ONLY.
// ---------------------------------------------------------------------------
__global__ __launch_bounds__(128) void norm_rope_k(bf16* __restrict__ k,
                                                   const float* __restrict__ pe,
                                                   const float* __restrict__ knw)
{
    const int s  = blockIdx.x;
    const int hh = blockIdx.y;
    const int b  = blockIdx.z;
    const int d  = threadIdx.x;

    bf16* buf = k + (size_t)(b * SEQ + s) * 1024 + hh * HD;

    float x = (float)buf[d];
    float ss = x * x;
    #pragma unroll
    for (int m = 32; m; m >>= 1) ss += __shfl_xor(ss, m);

    __shared__ float red[2];
    __shared__ float nv[128];
    if ((d & 63) == 0) red[d >> 6] = ss;
    __syncthreads();
    float var = (red[0] + red[1]) * (1.0f / 128.0f);
    float nx = x * rsqrtf(var + 1e-6f) * knw[d];
    nv[d] = nx;
    __syncthreads();

    const float* pev = pe + ((size_t)b * SEQ + s) * HD;
    float o;
    if (d < 64) {
        o = nx * pev[d] - nv[d + 64] * pev[64 + d];
    } else {
        o = nv[d - 64] * pev[d] + nx * pev[d - 64];
    }
    buf[d] = (bf16)o;
}

// ---------------------------------------------------------------------------
// Flash attention, causal, GQA rep=2.  64q rows per block (wave owns 16),
// 64-key tiles, static-max softmax, register prefetch across the barrier.
// Round-0 verified structure with ONE change: the per-wave P scratch is
// OVERLAID onto the Ks buffer (P is only live after QK^T finishes reading
// Ks).  LDS drops 45056 -> 35840 B => 4 blocks/CU (grid provides exactly 4),
// 16 waves/CU vs round-0's 12.  The overlay needs a raw s_barrier between
// "all waves done reading Ks" and "P writes" -- raw (not __syncthreads) so
// the compiler does NOT drain vmcnt and the K/V register prefetch stays in
// flight across it.  asm memory fences pin ds-op ordering around it.
// ---------------------------------------------------------------------------
__global__ __launch_bounds__(256, 4) void fattn(bf16* __restrict__ O,
                                                const bf16* __restrict__ Q,
                                                const bf16* __restrict__ Kh,
                                                const bf16* __restrict__ Vtg,
                                                const float* __restrict__ pe,
                                                const float* __restrict__ qnw)
{
    const int h    = blockIdx.y;
    const int b    = blockIdx.z;
    const int qblk = (h & 8) ? (int)blockIdx.x
                             : ((int)gridDim.x - 1 - (int)blockIdx.x);
    const int kv   = h >> 1;

    const int tid  = threadIdx.x;
    const int wv   = tid >> 6;
    const int lane = tid & 63;
    const int quad = lane >> 4;
    const int c    = lane & 15;

    __shared__ bf16 Ks[64 * 136];        // [key][d]; low 9216B double as P scratch
    __shared__ bf16 Vs[128 * 72];        // [d][key]

    const int qw = qblk * 64 + wv * 16;

    // ---- prologue: load raw q row, RMSNorm + RoPE in registers ----
    bf16x8 qf[4];
    {
        const bf16* qp = Q + (size_t)(b * SEQ + qw + c) * 2048 + h * HD + quad * 8;
        float qv[4][8];
        float ss = 0.0f;
        #pragma unroll
        for (int t = 0; t < 4; t++) {
            bf16x8 raw = *(const bf16x8*)(qp + t * 32);
            #pragma unroll
            for (int j = 0; j < 8; j++) { qv[t][j] = (float)raw[j]; ss += qv[t][j] * qv[t][j]; }
        }
        // lanes c, c+16, c+32, c+48 hold the same q row
        ss += __shfl_xor(ss, 16);
        ss += __shfl_xor(ss, 32);
        const float inv = rsqrtf(ss * (1.0f / 128.0f) + 1e-6f);
        const float* pev = pe + (size_t)(b * SEQ + qw + c) * HD + quad * 8;
        float nx[4][8], pv[4][8];
        #pragma unroll
        for (int t = 0; t < 4; t++)
            #pragma unroll
            for (int j = 0; j < 8; j++) {
                pv[t][j] = pev[t * 32 + j];
                nx[t][j] = qv[t][j] * inv * qnw[t * 32 + quad * 8 + j];
            }
        #pragma unroll
        for (int t = 0; t < 2; t++)
            #pragma unroll
            for (int j = 0; j < 8; j++) {
                qf[t][j]     = (bf16)(nx[t][j] * pv[t][j]     - nx[t + 2][j] * pv[t + 2][j]);
                qf[t + 2][j] = (bf16)(nx[t][j] * pv[t + 2][j] + nx[t + 2][j] * pv[t][j]);
            }
    }

    floatx4 o_acc[8] = {};
    float l_part[4] = {};

    const bf16* kbase = Kh  + (size_t)b * SEQ * 1024 + kv * HD;        // + s*1024
    const bf16* vbase = Vtg + ((size_t)b * 1024 + kv * HD) * 2048;     // + d*2048

    const int kr  = tid >> 2, ksc = (tid & 3) * 32;   // K staging: 64 rows x 128
    const int vd  = tid >> 1, vkc = (tid & 1) * 32;   // V^T staging: 128 rows x 64
    bf16* psw = &Ks[wv * 16 * 72];                    // P overlay inside Ks
    const int nkt = qblk + 1;
    const float kS = 0.08838834764831845f * 1.4426950408889634f;  // scale*log2e
    const float kB = 11.5f * 1.4426950408889634f;                 // M*log2e

    // ---- load tile 0 into registers ----
    bf16x8 kreg[4], vreg[4];
    {
        const bf16* kp = kbase + (size_t)kr * 1024 + ksc;
        const bf16* vp = vbase + (size_t)vd * 2048 + vkc;
        #pragma unroll
        for (int i = 0; i < 4; i++) kreg[i] = *(const bf16x8*)(kp + i * 8);
        #pragma unroll
        for (int i = 0; i < 4; i++) vreg[i] = *(const bf16x8*)(vp + i * 8);
    }

    for (int kt = 0; kt < nkt; kt++) {
        const int k0 = kt * 64;
        // ---- commit prefetched tile to LDS ----
        #pragma unroll
        for (int i = 0; i < 4; i++)
            *(bf16x8*)(&Ks[kr * 136 + ksc + i * 8]) = kreg[i];
        #pragma unroll
        for (int i = 0; i < 4; i++)
            *(bf16x8*)(&Vs[vd * 72 + vkc + i * 8]) = vreg[i];
        __syncthreads();

        // ---- prefetch next tile (latency covered by compute below) ----
        if (kt + 1 < nkt) {
            const bf16* kp = kbase + (size_t)(k0 + 64 + kr) * 1024 + ksc;
            const bf16* vp = vbase + (size_t)vd * 2048 + (k0 + 64) + vkc;
            #pragma unroll
            for (int i = 0; i < 4; i++) kreg[i] = *(const bf16x8*)(kp + i * 8);
            #pragma unroll
            for (int i = 0; i < 4; i++) vreg[i] = *(const bf16x8*)(vp + i * 8);
        }

        // ---- QK^T: 16 q-rows x 64 keys ----
        floatx4 sc[4] = {};
        #pragma unroll
        for (int t = 0; t < 4; t++) {
            #pragma unroll
            for (int g = 0; g < 4; g++) {
                bf16x8 kf = *(const bf16x8*)(&Ks[(g * 16 + c) * 136 + t * 32 + quad * 8]);
                sc[g] = __builtin_amdgcn_mfma_f32_16x16x32_bf16(qf[t], kf, sc[g], 0, 0, 0);
            }
        }

        // ---- raw barrier: all waves done reading Ks before P overlay writes.
        // No vmcnt drain (prefetch stays in flight); lgkm already consumed by
        // the MFMAs above.  Fences stop ds-op motion across the barrier. ----
        asm volatile("" ::: "memory");
        __builtin_amdgcn_s_barrier();
        asm volatile("" ::: "memory");

        // ---- static-max softmax + P store (no reductions) ----
        const bool last = (kt == nkt - 1);
        #pragma unroll
        for (int r = 0; r < 4; r++) {
            const int qrow = qw + quad * 4 + r;
            #pragma unroll
            for (int g = 0; g < 4; g++) {
                float p = exp2f(sc[g][r] * kS - kB);
                if (last && (k0 + g * 16 + c > qrow)) p = 0.0f;
                l_part[r] += p;
                psw[(quad * 4 + r) * 72 + g * 16 + c] = (bf16)p;
            }
        }
        // drain ds_writes before wave-local ds_reads (vmcnt untouched)
        asm volatile("s_waitcnt lgkmcnt(0)" ::: "memory");
        bf16x8 pf0 = *(const bf16x8*)(&psw[c * 72 + quad * 8]);
        bf16x8 pf1 = *(const bf16x8*)(&psw[c * 72 + 32 + quad * 8]);

        // ---- PV ----
        #pragma unroll
        for (int f = 0; f < 8; f++) {
            bf16x8 vf0 = *(const bf16x8*)(&Vs[(f * 16 + c) * 72 + quad * 8]);
            bf16x8 vf1 = *(const bf16x8*)(&Vs[(f * 16 + c) * 72 + 32 + quad * 8]);
            o_acc[f] = __builtin_amdgcn_mfma_f32_16x16x32_bf16(pf0, vf0, o_acc[f], 0, 0, 0);
            o_acc[f] = __builtin_amdgcn_mfma_f32_16x16x32_bf16(pf1, vf1, o_acc[f], 0, 0, 0);
        }
        __syncthreads();
    }

    // ---- epilogue: one l-reduction per row, normalize, store ----
    #pragma unroll
    for (int r = 0; r < 4; r++) {
        float l = l_part[r];
        #pragma unroll
        for (int msk = 8; msk; msk >>= 1) l += __shfl_xor(l, msk);
        const float inv = 1.0f / l;
        bf16* op = O + (size_t)(b * SEQ + qw + quad * 4 + r) * 2048 + h * HD;
        #pragma unroll
        for (int f = 0; f < 8; f++) op[f * 16 + c] = (bf16)(o_acc[f][r] * inv);
    }
}

// ---------------------------------------------------------------------------
extern "C" void kernel_launch(void* const* d_in, const int* in_sizes, int n_in,
                              void* d_out, int out_size, void* d_ws, size_t ws_size,
                              hipStream_t stream)
{
    const float* x   = (const float*)d_in[0];
    const float* pe  = (const float*)d_in[1];
    const float* qw  = (const float*)d_in[2];
    const float* kw  = (const float*)d_in[3];
    const float* vw  = (const float*)d_in[4];
    const float* ow  = (const float*)d_in[5];
    const float* qnw = (const float*)d_in[6];
    const float* knw = (const float*)d_in[7];
    float* out = (float*)d_out;

    bf16* qb = (bf16*)d_ws;          // [B][S][2048]   row-major (raw q)
    bf16* kb = qb + XN;              // [B][S][1024]   row-major
    bf16* vt = kb + KWN * 2;         // [B][1024][2048] V^T
    bf16* ab = vt + VWN * 2;         // [B][S][2048]   row-major
    bf16* cvt_base = ab + XN;

    const bool fit = ws_size >= (size_t)92274688;
    const int M = BATCH * SEQ;

    if (fit) {
        bf16* xb  = cvt_base;
        bf16* qwb = xb  + XN;
        bf16* owb = qwb + QWN + KWN + VWN;

        cvt_all<<<10240, 256, 0, stream>>>(xb, x, qw, kw, vw, ow);

        gemm128<1, 1, 3><<<dim3(32, 32), 256, 0, stream>>>(qb, xb, qwb, M, 4096, 2048);

        norm_rope_k<<<dim3(SEQ, NKV, BATCH), 128, 0, stream>>>(kb, pe, knw);
        fattn<<<dim3(SEQ / 64, NH, BATCH), 256, 0, stream>>>(ab, qb, kb, vt, pe, qnw);

        gemm_o64<<<dim3(32, 32), 256, 0, stream>>>(out, ab, owb, M, 2048, 2048);
    } else {
        gemm128<0, 0, 1><<<dim3(32, 16), 256, 0, stream>>>(qb, x, qw, M, 2048, 2048);
        gemm128<0, 0, 1><<<dim3(32,  8), 256, 0, stream>>>(kb, x, kw, M, 1024, 2048);
        gemm128<0, 0, 2><<<dim3(32,  8), 256, 0, stream>>>(vt, x, vw, M, 1024, 2048);

        norm_rope_k<<<dim3(SEQ, NKV, BATCH), 128, 0, stream>>>(kb, pe, knw);
        fattn<<<dim3(SEQ / 64, NH, BATCH), 256, 0, stream>>>(ab, qb, kb, vt, pe, qnw);

        gemm128<0, 0, 0><<<dim3(32, 16), 256, 0, stream>>>(out, ab, ow, M, 2048, 2048);
    }
}

// Round 6
// 401.597 us; speedup vs baseline: 1.0966x; 1.0726x over previous
//
#include <hip/hip_runtime.h>
#include <hip/hip_bf16.h>

#define BATCH 2
#define SEQ   2048
#define HID   2048
#define NH    16
#define NKV   8
#define HD    128

typedef __bf16 bf16;
typedef bf16  bf16x8  __attribute__((ext_vector_type(8)));
typedef bf16  bf16x4  __attribute__((ext_vector_type(4)));
typedef float floatx4 __attribute__((ext_vector_type(4)));

typedef __attribute__((address_space(3))) void lds_void;
typedef const __attribute__((address_space(1))) void gmem_void;

__device__ inline void async16(const void* g, void* l) {
    __builtin_amdgcn_global_load_lds((gmem_void*)g, (lds_void*)l, 16, 0, 0);
}

// workspace layout constants (elements)
#define XN  8388608u
#define QWN 4194304u
#define KWN 2097152u
#define VWN 2097152u
#define OWN 4194304u

// ---------------------------------------------------------------------------
// Fused f32 -> bf16 convert for x + all four weights in ONE launch.
// ---------------------------------------------------------------------------
__global__ __launch_bounds__(256) void cvt_all(bf16* __restrict__ dst,
                                               const float* __restrict__ x,
                                               const float* __restrict__ qw,
                                               const float* __restrict__ kw,
                                               const float* __restrict__ vw,
                                               const float* __restrict__ ow)
{
    const int blk = blockIdx.x;
    const float* src;
    size_t off;
    if (blk < 4096)      { src = x;  off = (size_t)blk * 2048; }
    else if (blk < 6144) { src = qw; off = (size_t)(blk - 4096) * 2048; }
    else if (blk < 7168) { src = kw; off = (size_t)(blk - 6144) * 2048; }
    else if (blk < 8192) { src = vw; off = (size_t)(blk - 7168) * 2048; }
    else                 { src = ow; off = (size_t)(blk - 8192) * 2048; }

    const int t = threadIdx.x * 8;
    const float4* p = (const float4*)(src + off + t);
    float4 u0 = p[0], u1 = p[1];
    bf16x8 v;
    v[0] = (bf16)u0.x; v[1] = (bf16)u0.y; v[2] = (bf16)u0.z; v[3] = (bf16)u0.w;
    v[4] = (bf16)u1.x; v[5] = (bf16)u1.y; v[6] = (bf16)u1.z; v[7] = (bf16)u1.w;
    *(bf16x8*)(dst + (size_t)blk * 2048 + t) = v;
}

// ---------------------------------------------------------------------------
// GEMM  C = A[M,K] * W[N,K]^T, 128x128 tile, BK=64.
// ---------------------------------------------------------------------------
template <int AMODE, int WMODE, int CMODE>
__global__ __launch_bounds__(256) void gemm128(void* __restrict__ Cp,
                                               const void* __restrict__ Ap,
                                               const void* __restrict__ Wp,
                                               int M, int N, int K)
{
    __shared__ bf16 As[128 * 64];
    __shared__ bf16 Ws[128 * 64];

    const int tid  = threadIdx.x;
    const int wv   = tid >> 6;
    const int lane = tid & 63;
    const int quad = lane >> 4;
    const int c    = lane & 15;

    const int m0 = blockIdx.x * 128;
    const int n0 = blockIdx.y * 128;
    const int wm = (wv >> 1) * 64;
    const int wn = (wv & 1) * 64;

    const int arow = lane >> 3;
    const int acol = (lane & 7) * 8;

    floatx4 acc[4][4] = {};

    for (int k0 = 0; k0 < K; k0 += 64) {
        if constexpr (AMODE == 0) {
            const float* A = (const float*)Ap;
            #pragma unroll
            for (int it = 0; it < 4; it++) {
                int row = it * 32 + (tid >> 3);
                int col = (tid & 7) * 8;
                const float4* p = (const float4*)(A + (size_t)(m0 + row) * K + k0 + col);
                float4 u0 = p[0], u1 = p[1];
                bf16x8 v;
                v[0] = (bf16)u0.x; v[1] = (bf16)u0.y; v[2] = (bf16)u0.z; v[3] = (bf16)u0.w;
                v[4] = (bf16)u1.x; v[5] = (bf16)u1.y; v[6] = (bf16)u1.z; v[7] = (bf16)u1.w;
                *(bf16x8*)(&As[row * 64 + col]) = v;
            }
        } else {
            const bf16* A = (const bf16*)Ap;
            #pragma unroll
            for (int ch = 0; ch < 4; ch++) {
                int row = wv * 32 + ch * 8 + arow;
                async16(A + (size_t)(m0 + row) * K + k0 + acol,
                        &As[(wv * 32 + ch * 8) * 64]);
            }
        }
        if constexpr (WMODE == 0) {
            const float* W = (const float*)Wp;
            #pragma unroll
            for (int it = 0; it < 4; it++) {
                int row = it * 32 + (tid >> 3);
                int col = (tid & 7) * 8;
                const float4* p = (const float4*)(W + (size_t)(n0 + row) * K + k0 + col);
                float4 u0 = p[0], u1 = p[1];
                bf16x8 v;
                v[0] = (bf16)u0.x; v[1] = (bf16)u0.y; v[2] = (bf16)u0.z; v[3] = (bf16)u0.w;
                v[4] = (bf16)u1.x; v[5] = (bf16)u1.y; v[6] = (bf16)u1.z; v[7] = (bf16)u1.w;
                *(bf16x8*)(&Ws[row * 64 + col]) = v;
            }
        } else {
            const bf16* W = (const bf16*)Wp;
            #pragma unroll
            for (int ch = 0; ch < 4; ch++) {
                int row = wv * 32 + ch * 8 + arow;
                async16(W + (size_t)(n0 + row) * K + k0 + acol,
                        &Ws[(wv * 32 + ch * 8) * 64]);
            }
        }
        __syncthreads();

        #pragma unroll
        for (int t = 0; t < 2; t++) {
            bf16x8 af[4], bw[4];
            #pragma unroll
            for (int i = 0; i < 4; i++)
                af[i] = *(const bf16x8*)(&As[(wm + i * 16 + c) * 64 + t * 32 + quad * 8]);
            #pragma unroll
            for (int j = 0; j < 4; j++)
                bw[j] = *(const bf16x8*)(&Ws[(wn + j * 16 + c) * 64 + t * 32 + quad * 8]);
            #pragma unroll
            for (int i = 0; i < 4; i++)
                #pragma unroll
                for (int j = 0; j < 4; j++)
                    acc[i][j] = __builtin_amdgcn_mfma_f32_16x16x32_bf16(af[i], bw[j], acc[i][j], 0, 0, 0);
        }
        __syncthreads();
    }

    if constexpr (CMODE == 0) {
        float* C = (float*)Cp;
        #pragma unroll
        for (int i = 0; i < 4; i++)
            #pragma unroll
            for (int j = 0; j < 4; j++)
                #pragma unroll
                for (int r = 0; r < 4; r++) {
                    int m = m0 + wm + i * 16 + quad * 4 + r;
                    int n = n0 + wn + j * 16 + c;
                    C[(size_t)m * N + n] = acc[i][j][r];
                }
    } else if constexpr (CMODE == 1) {
        bf16* C = (bf16*)Cp;
        #pragma unroll
        for (int i = 0; i < 4; i++)
            #pragma unroll
            for (int j = 0; j < 4; j++)
                #pragma unroll
                for (int r = 0; r < 4; r++) {
                    int m = m0 + wm + i * 16 + quad * 4 + r;
                    int n = n0 + wn + j * 16 + c;
                    C[(size_t)m * N + n] = (bf16)acc[i][j][r];
                }
    } else if constexpr (CMODE == 2) {
        bf16* C = (bf16*)Cp;
        const int b = m0 >> 11;
        #pragma unroll
        for (int j = 0; j < 4; j++) {
            int n = n0 + wn + j * 16 + c;
            size_t base = ((size_t)b * N + n) * 2048;
            #pragma unroll
            for (int i = 0; i < 4; i++) {
                int s0 = (m0 & 2047) + wm + i * 16 + quad * 4;
                bf16x4 v;
                #pragma unroll
                for (int r = 0; r < 4; r++) v[r] = (bf16)acc[i][j][r];
                *(bf16x4*)(&C[base + s0]) = v;
            }
        }
    } else {
        bf16* Cq = (bf16*)Cp;
        if (n0 < 2048) {
            #pragma unroll
            for (int i = 0; i < 4; i++)
                #pragma unroll
                for (int j = 0; j < 4; j++)
                    #pragma unroll
                    for (int r = 0; r < 4; r++) {
                        int m = m0 + wm + i * 16 + quad * 4 + r;
                        int n = n0 + wn + j * 16 + c;
                        Cq[(size_t)m * 2048 + n] = (bf16)acc[i][j][r];
                    }
        } else if (n0 < 3072) {
            bf16* Ck = Cq + XN;
            #pragma unroll
            for (int i = 0; i < 4; i++)
                #pragma unroll
                for (int j = 0; j < 4; j++)
                    #pragma unroll
                    for (int r = 0; r < 4; r++) {
                        int m = m0 + wm + i * 16 + quad * 4 + r;
                        int n = n0 - 2048 + wn + j * 16 + c;
                        Ck[(size_t)m * 1024 + n] = (bf16)acc[i][j][r];
                    }
        } else {
            bf16* Cv = Cq + XN + QWN;
            const int b = m0 >> 11;
            #pragma unroll
            for (int j = 0; j < 4; j++) {
                int n = n0 - 3072 + wn + j * 16 + c;
                size_t base = ((size_t)b * 1024 + n) * 2048;
                #pragma unroll
                for (int i = 0; i < 4; i++) {
                    int s0 = (m0 & 2047) + wm + i * 16 + quad * 4;
                    bf16x4 v;
                    #pragma unroll
                    for (int r = 0; r < 4; r++) v[r] = (bf16)acc[i][j][r];
                    *(bf16x4*)(&Cv[base + s0]) = v;
                }
            }
        }
    }
}

// ---------------------------------------------------------------------------
// O-projection GEMM: 128x64 tile, BK=64.
// ---------------------------------------------------------------------------
__global__ __launch_bounds__(256) void gemm_o64(float* __restrict__ C,
                                                const bf16* __restrict__ A,
                                                const bf16* __restrict__ W,
                                                int M, int N, int K)
{
    __shared__ bf16 As[128 * 64];
    __shared__ bf16 Ws[64 * 64];

    const int tid  = threadIdx.x;
    const int wv   = tid >> 6;
    const int lane = tid & 63;
    const int quad = lane >> 4;
    const int c    = lane & 15;

    const int m0 = blockIdx.x * 128;
    const int n0 = blockIdx.y * 64;
    const int wm = (wv >> 1) * 64;
    const int wn = (wv & 1) * 32;

    const int arow = lane >> 3;
    const int acol = (lane & 7) * 8;

    floatx4 acc[4][2] = {};

    for (int k0 = 0; k0 < K; k0 += 64) {
        #pragma unroll
        for (int ch = 0; ch < 4; ch++) {
            int row = wv * 32 + ch * 8 + arow;
            async16(A + (size_t)(m0 + row) * K + k0 + acol,
                    &As[(wv * 32 + ch * 8) * 64]);
        }
        #pragma unroll
        for (int ch = 0; ch < 2; ch++) {
            int row = wv * 16 + ch * 8 + arow;
            async16(W + (size_t)(n0 + row) * K + k0 + acol,
                    &Ws[(wv * 16 + ch * 8) * 64]);
        }
        __syncthreads();

        #pragma unroll
        for (int t = 0; t < 2; t++) {
            bf16x8 af[4], bw[2];
            #pragma unroll
            for (int i = 0; i < 4; i++)
                af[i] = *(const bf16x8*)(&As[(wm + i * 16 + c) * 64 + t * 32 + quad * 8]);
            #pragma unroll
            for (int j = 0; j < 2; j++)
                bw[j] = *(const bf16x8*)(&Ws[(wn + j * 16 + c) * 64 + t * 32 + quad * 8]);
            #pragma unroll
            for (int i = 0; i < 4; i++)
                #pragma unroll
                for (int j = 0; j < 2; j++)
                    acc[i][j] = __builtin_amdgcn_mfma_f32_16x16x32_bf16(af[i], bw[j], acc[i][j], 0, 0, 0);
        }
        __syncthreads();
    }

    #pragma unroll
    for (int i = 0; i < 4; i++)
        #pragma unroll
        for (int j = 0; j < 2; j++)
            #pragma unroll
            for (int r = 0; r < 4; r++) {
                int m = m0 + wm + i * 16 + quad * 4 + r;
                int n = n0 + wn + j * 16 + c;
                C[(size_t)m * N + n] = acc[i][j][r];
            }
}

// ---------------------------------------------------------------------------
// RMSNorm(D=128) + RoPE for K ONLY.
// ---------------------------------------------------------------------------
__global__ __launch_bounds__(128) void norm_rope_k(bf16* __restrict__ k,
                                                   const float* __restrict__ pe,
                                                   const float* __restrict__ knw)
{
    const int s  = blockIdx.x;
    const int hh = blockIdx.y;
    const int b  = blockIdx.z;
    const int d  = threadIdx.x;

    bf16* buf = k + (size_t)(b * SEQ + s) * 1024 + hh * HD;

    float x = (float)buf[d];
    float ss = x * x;
    #pragma unroll
    for (int m = 32; m; m >>= 1) ss += __shfl_xor(ss, m);

    __shared__ float red[2];
    __shared__ float nv[128];
    if ((d & 63) == 0) red[d >> 6] = ss;
    __syncthreads();
    float var = (red[0] + red[1]) * (1.0f / 128.0f);
    float nx = x * rsqrtf(var + 1e-6f) * knw[d];
    nv[d] = nx;
    __syncthreads();

    const float* pev = pe + ((size_t)b * SEQ + s) * HD;
    float o;
    if (d < 64) {
        o = nx * pev[d] - nv[d + 64] * pev[64 + d];
    } else {
        o = nv[d - 64] * pev[d] + nx * pev[d - 64];
    }
    buf[d] = (bf16)o;
}

// ---------------------------------------------------------------------------
// Flash attention, causal, GQA rep=2.  64q rows per block (wave owns 16),
// 64-key tiles, static-max softmax, register prefetch across the barrier.
// P scratch OVERLAID onto Ks (P only live after QK^T finishes reading Ks);
// LDS 35840 B => 4 blocks/CU.  Raw s_barrier (no vmcnt drain) separates
// Ks reads from P overlay writes.  NO min-waves launch bound: round-5's
// (256,4) forced VGPR to 64 and spilled (WRITE_SIZE 16->143 MB).  Natural
// allocation (~88 VGPR) already sustains 4 waves/SIMD.
// ---------------------------------------------------------------------------
__global__ __launch_bounds__(256) void fattn(bf16* __restrict__ O,
                                             const bf16* __restrict__ Q,
                                             const bf16* __restrict__ Kh,
                                             const bf16* __restrict__ Vtg,
                                             const float* __restrict__ pe,
                                             const float* __restrict__ qnw)
{
    const int h    = blockIdx.y;
    const int b    = blockIdx.z;
    const int qblk = (h & 8) ? (int)blockIdx.x
                             : ((int)gridDim.x - 1 - (int)blockIdx.x);
    const int kv   = h >> 1;

    const int tid  = threadIdx.x;
    const int wv   = tid >> 6;
    const int lane = tid & 63;
    const int quad = lane >> 4;
    const int c    = lane & 15;

    __shared__ bf16 Ks[64 * 136];        // [key][d]; low 9216B double as P scratch
    __shared__ bf16 Vs[128 * 72];        // [d][key]

    const int qw = qblk * 64 + wv * 16;

    // ---- prologue: load raw q row, RMSNorm + RoPE in registers ----
    bf16x8 qf[4];
    {
        const bf16* qp = Q + (size_t)(b * SEQ + qw + c) * 2048 + h * HD + quad * 8;
        float qv[4][8];
        float ss = 0.0f;
        #pragma unroll
        for (int t = 0; t < 4; t++) {
            bf16x8 raw = *(const bf16x8*)(qp + t * 32);
            #pragma unroll
            for (int j = 0; j < 8; j++) { qv[t][j] = (float)raw[j]; ss += qv[t][j] * qv[t][j]; }
        }
        // lanes c, c+16, c+32, c+48 hold the same q row
        ss += __shfl_xor(ss, 16);
        ss += __shfl_xor(ss, 32);
        const float inv = rsqrtf(ss * (1.0f / 128.0f) + 1e-6f);
        const float* pev = pe + (size_t)(b * SEQ + qw + c) * HD + quad * 8;
        float nx[4][8], pv[4][8];
        #pragma unroll
        for (int t = 0; t < 4; t++)
            #pragma unroll
            for (int j = 0; j < 8; j++) {
                pv[t][j] = pev[t * 32 + j];
                nx[t][j] = qv[t][j] * inv * qnw[t * 32 + quad * 8 + j];
            }
        #pragma unroll
        for (int t = 0; t < 2; t++)
            #pragma unroll
            for (int j = 0; j < 8; j++) {
                qf[t][j]     = (bf16)(nx[t][j] * pv[t][j]     - nx[t + 2][j] * pv[t + 2][j]);
                qf[t + 2][j] = (bf16)(nx[t][j] * pv[t + 2][j] + nx[t + 2][j] * pv[t][j]);
            }
    }

    floatx4 o_acc[8] = {};
    float l_part[4] = {};

    const bf16* kbase = Kh  + (size_t)b * SEQ * 1024 + kv * HD;        // + s*1024
    const bf16* vbase = Vtg + ((size_t)b * 1024 + kv * HD) * 2048;     // + d*2048

    const int kr  = tid >> 2, ksc = (tid & 3) * 32;   // K staging: 64 rows x 128
    const int vd  = tid >> 1, vkc = (tid & 1) * 32;   // V^T staging: 128 rows x 64
    bf16* psw = &Ks[wv * 16 * 72];                    // P overlay inside Ks
    const int nkt = qblk + 1;
    const float kS = 0.08838834764831845f * 1.4426950408889634f;  // scale*log2e
    const float kB = 11.5f * 1.4426950408889634f;                 // M*log2e

    // ---- load tile 0 into registers ----
    bf16x8 kreg[4], vreg[4];
    {
        const bf16* kp = kbase + (size_t)kr * 1024 + ksc;
        const bf16* vp = vbase + (size_t)vd * 2048 + vkc;
        #pragma unroll
        for (int i = 0; i < 4; i++) kreg[i] = *(const bf16x8*)(kp + i * 8);
        #pragma unroll
        for (int i = 0; i < 4; i++) vreg[i] = *(const bf16x8*)(vp + i * 8);
    }

    for (int kt = 0; kt < nkt; kt++) {
        const int k0 = kt * 64;
        // ---- commit prefetched tile to LDS ----
        #pragma unroll
        for (int i = 0; i < 4; i++)
            *(bf16x8*)(&Ks[kr * 136 + ksc + i * 8]) = kreg[i];
        #pragma unroll
        for (int i = 0; i < 4; i++)
            *(bf16x8*)(&Vs[vd * 72 + vkc + i * 8]) = vreg[i];
        __syncthreads();

        // ---- prefetch next tile (latency covered by compute below) ----
        if (kt + 1 < nkt) {
            const bf16* kp = kbase + (size_t)(k0 + 64 + kr) * 1024 + ksc;
            const bf16* vp = vbase + (size_t)vd * 2048 + (k0 + 64) + vkc;
            #pragma unroll
            for (int i = 0; i < 4; i++) kreg[i] = *(const bf16x8*)(kp + i * 8);
            #pragma unroll
            for (int i = 0; i < 4; i++) vreg[i] = *(const bf16x8*)(vp + i * 8);
        }

        // ---- QK^T: 16 q-rows x 64 keys ----
        floatx4 sc[4] = {};
        #pragma unroll
        for (int t = 0; t < 4; t++) {
            #pragma unroll
            for (int g = 0; g < 4; g++) {
                bf16x8 kf = *(const bf16x8*)(&Ks[(g * 16 + c) * 136 + t * 32 + quad * 8]);
                sc[g] = __builtin_amdgcn_mfma_f32_16x16x32_bf16(qf[t], kf, sc[g], 0, 0, 0);
            }
        }

        // ---- raw barrier: all waves done reading Ks before P overlay writes.
        // No vmcnt drain (prefetch stays in flight); lgkm already consumed by
        // the MFMAs above.  Fences stop ds-op motion across the barrier. ----
        asm volatile("" ::: "memory");
        __builtin_amdgcn_s_barrier();
        asm volatile("" ::: "memory");

        // ---- static-max softmax + P store (no reductions) ----
        const bool last = (kt == nkt - 1);
        #pragma unroll
        for (int r = 0; r < 4; r++) {
            const int qrow = qw + quad * 4 + r;
            #pragma unroll
            for (int g = 0; g < 4; g++) {
                float p = exp2f(sc[g][r] * kS - kB);
                if (last && (k0 + g * 16 + c > qrow)) p = 0.0f;
                l_part[r] += p;
                psw[(quad * 4 + r) * 72 + g * 16 + c] = (bf16)p;
            }
        }
        // drain ds_writes before wave-local ds_reads (vmcnt untouched)
        asm volatile("s_waitcnt lgkmcnt(0)" ::: "memory");
        bf16x8 pf0 = *(const bf16x8*)(&psw[c * 72 + quad * 8]);
        bf16x8 pf1 = *(const bf16x8*)(&psw[c * 72 + 32 + quad * 8]);

        // ---- PV ----
        #pragma unroll
        for (int f = 0; f < 8; f++) {
            bf16x8 vf0 = *(const bf16x8*)(&Vs[(f * 16 + c) * 72 + quad * 8]);
            bf16x8 vf1 = *(const bf16x8*)(&Vs[(f * 16 + c) * 72 + 32 + quad * 8]);
            o_acc[f] = __builtin_amdgcn_mfma_f32_16x16x32_bf16(pf0, vf0, o_acc[f], 0, 0, 0);
            o_acc[f] = __builtin_amdgcn_mfma_f32_16x16x32_bf16(pf1, vf1, o_acc[f], 0, 0, 0);
        }
        __syncthreads();
    }

    // ---- epilogue: one l-reduction per row, normalize, store ----
    #pragma unroll
    for (int r = 0; r < 4; r++) {
        float l = l_part[r];
        #pragma unroll
        for (int msk = 8; msk; msk >>= 1) l += __shfl_xor(l, msk);
        const float inv = 1.0f / l;
        bf16* op = O + (size_t)(b * SEQ + qw + quad * 4 + r) * 2048 + h * HD;
        #pragma unroll
        for (int f = 0; f < 8; f++) op[f * 16 + c] = (bf16)(o_acc[f][r] * inv);
    }
}

// ---------------------------------------------------------------------------
extern "C" void kernel_launch(void* const* d_in, const int* in_sizes, int n_in,
                              void* d_out, int out_size, void* d_ws, size_t ws_size,
                              hipStream_t stream)
{
    const float* x   = (const float*)d_in[0];
    const float* pe  = (const float*)d_in[1];
    const float* qw  = (const float*)d_in[2];
    const float* kw  = (const float*)d_in[3];
    const float* vw  = (const float*)d_in[4];
    const float* ow  = (const float*)d_in[5];
    const float* qnw = (const float*)d_in[6];
    const float* knw = (const float*)d_in[7];
    float* out = (float*)d_out;

    bf16* qb = (bf16*)d_ws;          // [B][S][2048]   row-major (raw q)
    bf16* kb = qb + XN;              // [B][S][1024]   row-major
    bf16* vt = kb + KWN * 2;         // [B][1024][2048] V^T
    bf16* ab = vt + VWN * 2;         // [B][S][2048]   row-major
    bf16* cvt_base = ab + XN;

    const bool fit = ws_size >= (size_t)92274688;
    const int M = BATCH * SEQ;

    if (fit) {
        bf16* xb  = cvt_base;
        bf16* qwb = xb  + XN;
        bf16* owb = qwb + QWN + KWN + VWN;

        cvt_all<<<10240, 256, 0, stream>>>(xb, x, qw, kw, vw, ow);

        gemm128<1, 1, 3><<<dim3(32, 32), 256, 0, stream>>>(qb, xb, qwb, M, 4096, 2048);

        norm_rope_k<<<dim3(SEQ, NKV, BATCH), 128, 0, stream>>>(kb, pe, knw);
        fattn<<<dim3(SEQ / 64, NH, BATCH), 256, 0, stream>>>(ab, qb, kb, vt, pe, qnw);

        gemm_o64<<<dim3(32, 32), 256, 0, stream>>>(out, ab, owb, M, 2048, 2048);
    } else {
        gemm128<0, 0, 1><<<dim3(32, 16), 256, 0, stream>>>(qb, x, qw, M, 2048, 2048);
        gemm128<0, 0, 1><<<dim3(32,  8), 256, 0, stream>>>(kb, x, kw, M, 1024, 2048);
        gemm128<0, 0, 2><<<dim3(32,  8), 256, 0, stream>>>(vt, x, vw, M, 1024, 2048);

        norm_rope_k<<<dim3(SEQ, NKV, BATCH), 128, 0, stream>>>(kb, pe, knw);
        fattn<<<dim3(SEQ / 64, NH, BATCH), 256, 0, stream>>>(ab, qb, kb, vt, pe, qnw);

        gemm128<0, 0, 0><<<dim3(32, 16), 256, 0, stream>>>(out, ab, ow, M, 2048, 2048);
    }
}

// Round 7
// 398.149 us; speedup vs baseline: 1.1061x; 1.0087x over previous
//
#include <hip/hip_runtime.h>
#include <hip/hip_bf16.h>

#define BATCH 2
#define SEQ   2048
#define HID   2048
#define NH    16
#define NKV   8
#define HD    128

typedef __bf16 bf16;
typedef bf16  bf16x8  __attribute__((ext_vector_type(8)));
typedef bf16  bf16x4  __attribute__((ext_vector_type(4)));
typedef float floatx4 __attribute__((ext_vector_type(4)));

typedef __attribute__((address_space(3))) void lds_void;
typedef const __attribute__((address_space(1))) void gmem_void;

__device__ inline void async16(const void* g, void* l) {
    __builtin_amdgcn_global_load_lds((gmem_void*)g, (lds_void*)l, 16, 0, 0);
}

// workspace layout constants (elements)
#define XN  8388608u
#define QWN 4194304u
#define KWN 2097152u
#define VWN 2097152u
#define OWN 4194304u

// ---------------------------------------------------------------------------
// Fused f32 -> bf16 convert for x + all four weights in ONE launch.
// ---------------------------------------------------------------------------
__global__ __launch_bounds__(256) void cvt_all(bf16* __restrict__ dst,
                                               const float* __restrict__ x,
                                               const float* __restrict__ qw,
                                               const float* __restrict__ kw,
                                               const float* __restrict__ vw,
                                               const float* __restrict__ ow)
{
    const int blk = blockIdx.x;
    const float* src;
    size_t off;
    if (blk < 4096)      { src = x;  off = (size_t)blk * 2048; }
    else if (blk < 6144) { src = qw; off = (size_t)(blk - 4096) * 2048; }
    else if (blk < 7168) { src = kw; off = (size_t)(blk - 6144) * 2048; }
    else if (blk < 8192) { src = vw; off = (size_t)(blk - 7168) * 2048; }
    else                 { src = ow; off = (size_t)(blk - 8192) * 2048; }

    const int t = threadIdx.x * 8;
    const float4* p = (const float4*)(src + off + t);
    float4 u0 = p[0], u1 = p[1];
    bf16x8 v;
    v[0] = (bf16)u0.x; v[1] = (bf16)u0.y; v[2] = (bf16)u0.z; v[3] = (bf16)u0.w;
    v[4] = (bf16)u1.x; v[5] = (bf16)u1.y; v[6] = (bf16)u1.z; v[7] = (bf16)u1.w;
    *(bf16x8*)(dst + (size_t)blk * 2048 + t) = v;
}

// ---------------------------------------------------------------------------
// GEMM  C = A[M,K] * W[N,K]^T, 128x128 tile, BK=64.
// ---------------------------------------------------------------------------
template <int AMODE, int WMODE, int CMODE>
__global__ __launch_bounds__(256) void gemm128(void* __restrict__ Cp,
                                               const void* __restrict__ Ap,
                                               const void* __restrict__ Wp,
                                               int M, int N, int K)
{
    __shared__ bf16 As[128 * 64];
    __shared__ bf16 Ws[128 * 64];

    const int tid  = threadIdx.x;
    const int wv   = tid >> 6;
    const int lane = tid & 63;
    const int quad = lane >> 4;
    const int c    = lane & 15;

    const int m0 = blockIdx.x * 128;
    const int n0 = blockIdx.y * 128;
    const int wm = (wv >> 1) * 64;
    const int wn = (wv & 1) * 64;

    const int arow = lane >> 3;
    const int acol = (lane & 7) * 8;

    floatx4 acc[4][4] = {};

    for (int k0 = 0; k0 < K; k0 += 64) {
        if constexpr (AMODE == 0) {
            const float* A = (const float*)Ap;
            #pragma unroll
            for (int it = 0; it < 4; it++) {
                int row = it * 32 + (tid >> 3);
                int col = (tid & 7) * 8;
                const float4* p = (const float4*)(A + (size_t)(m0 + row) * K + k0 + col);
                float4 u0 = p[0], u1 = p[1];
                bf16x8 v;
                v[0] = (bf16)u0.x; v[1] = (bf16)u0.y; v[2] = (bf16)u0.z; v[3] = (bf16)u0.w;
                v[4] = (bf16)u1.x; v[5] = (bf16)u1.y; v[6] = (bf16)u1.z; v[7] = (bf16)u1.w;
                *(bf16x8*)(&As[row * 64 + col]) = v;
            }
        } else {
            const bf16* A = (const bf16*)Ap;
            #pragma unroll
            for (int ch = 0; ch < 4; ch++) {
                int row = wv * 32 + ch * 8 + arow;
                async16(A + (size_t)(m0 + row) * K + k0 + acol,
                        &As[(wv * 32 + ch * 8) * 64]);
            }
        }
        if constexpr (WMODE == 0) {
            const float* W = (const float*)Wp;
            #pragma unroll
            for (int it = 0; it < 4; it++) {
                int row = it * 32 + (tid >> 3);
                int col = (tid & 7) * 8;
                const float4* p = (const float4*)(W + (size_t)(n0 + row) * K + k0 + col);
                float4 u0 = p[0], u1 = p[1];
                bf16x8 v;
                v[0] = (bf16)u0.x; v[1] = (bf16)u0.y; v[2] = (bf16)u0.z; v[3] = (bf16)u0.w;
                v[4] = (bf16)u1.x; v[5] = (bf16)u1.y; v[6] = (bf16)u1.z; v[7] = (bf16)u1.w;
                *(bf16x8*)(&Ws[row * 64 + col]) = v;
            }
        } else {
            const bf16* W = (const bf16*)Wp;
            #pragma unroll
            for (int ch = 0; ch < 4; ch++) {
                int row = wv * 32 + ch * 8 + arow;
                async16(W + (size_t)(n0 + row) * K + k0 + acol,
                        &Ws[(wv * 32 + ch * 8) * 64]);
            }
        }
        __syncthreads();

        #pragma unroll
        for (int t = 0; t < 2; t++) {
            bf16x8 af[4], bw[4];
            #pragma unroll
            for (int i = 0; i < 4; i++)
                af[i] = *(const bf16x8*)(&As[(wm + i * 16 + c) * 64 + t * 32 + quad * 8]);
            #pragma unroll
            for (int j = 0; j < 4; j++)
                bw[j] = *(const bf16x8*)(&Ws[(wn + j * 16 + c) * 64 + t * 32 + quad * 8]);
            #pragma unroll
            for (int i = 0; i < 4; i++)
                #pragma unroll
                for (int j = 0; j < 4; j++)
                    acc[i][j] = __builtin_amdgcn_mfma_f32_16x16x32_bf16(af[i], bw[j], acc[i][j], 0, 0, 0);
        }
        __syncthreads();
    }

    if constexpr (CMODE == 0) {
        float* C = (float*)Cp;
        #pragma unroll
        for (int i = 0; i < 4; i++)
            #pragma unroll
            for (int j = 0; j < 4; j++)
                #pragma unroll
                for (int r = 0; r < 4; r++) {
                    int m = m0 + wm + i * 16 + quad * 4 + r;
                    int n = n0 + wn + j * 16 + c;
                    C[(size_t)m * N + n] = acc[i][j][r];
                }
    } else if constexpr (CMODE == 1) {
        bf16* C = (bf16*)Cp;
        #pragma unroll
        for (int i = 0; i < 4; i++)
            #pragma unroll
            for (int j = 0; j < 4; j++)
                #pragma unroll
                for (int r = 0; r < 4; r++) {
                    int m = m0 + wm + i * 16 + quad * 4 + r;
                    int n = n0 + wn + j * 16 + c;
                    C[(size_t)m * N + n] = (bf16)acc[i][j][r];
                }
    } else if constexpr (CMODE == 2) {
        bf16* C = (bf16*)Cp;
        const int b = m0 >> 11;
        #pragma unroll
        for (int j = 0; j < 4; j++) {
            int n = n0 + wn + j * 16 + c;
            size_t base = ((size_t)b * N + n) * 2048;
            #pragma unroll
            for (int i = 0; i < 4; i++) {
                int s0 = (m0 & 2047) + wm + i * 16 + quad * 4;
                bf16x4 v;
                #pragma unroll
                for (int r = 0; r < 4; r++) v[r] = (bf16)acc[i][j][r];
                *(bf16x4*)(&C[base + s0]) = v;
            }
        }
    } else {
        bf16* Cq = (bf16*)Cp;
        if (n0 < 2048) {
            #pragma unroll
            for (int i = 0; i < 4; i++)
                #pragma unroll
                for (int j = 0; j < 4; j++)
                    #pragma unroll
                    for (int r = 0; r < 4; r++) {
                        int m = m0 + wm + i * 16 + quad * 4 + r;
                        int n = n0 + wn + j * 16 + c;
                        Cq[(size_t)m * 2048 + n] = (bf16)acc[i][j][r];
                    }
        } else if (n0 < 3072) {
            bf16* Ck = Cq + XN;
            #pragma unroll
            for (int i = 0; i < 4; i++)
                #pragma unroll
                for (int j = 0; j < 4; j++)
                    #pragma unroll
                    for (int r = 0; r < 4; r++) {
                        int m = m0 + wm + i * 16 + quad * 4 + r;
                        int n = n0 - 2048 + wn + j * 16 + c;
                        Ck[(size_t)m * 1024 + n] = (bf16)acc[i][j][r];
                    }
        } else {
            bf16* Cv = Cq + XN + QWN;
            const int b = m0 >> 11;
            #pragma unroll
            for (int j = 0; j < 4; j++) {
                int n = n0 - 3072 + wn + j * 16 + c;
                size_t base = ((size_t)b * 1024 + n) * 2048;
                #pragma unroll
                for (int i = 0; i < 4; i++) {
                    int s0 = (m0 & 2047) + wm + i * 16 + quad * 4;
                    bf16x4 v;
                    #pragma unroll
                    for (int r = 0; r < 4; r++) v[r] = (bf16)acc[i][j][r];
                    *(bf16x4*)(&Cv[base + s0]) = v;
                }
            }
        }
    }
}

// ---------------------------------------------------------------------------
// RMSNorm(D=128) + RoPE for K ONLY.
// ---------------------------------------------------------------------------
__global__ __launch_bounds__(128) void norm_rope_k(bf16* __restrict__ k,
                                                   const float* __restrict__ pe,
                                                   const float* __restrict__ knw)
{
    const int s  = blockIdx.x;
    const int hh = blockIdx.y;
    const int b  = blockIdx.z;
    const int d  = threadIdx.x;

    bf16* buf = k + (size_t)(b * SEQ + s) * 1024 + hh * HD;

    float x = (float)buf[d];
    float ss = x * x;
    #pragma unroll
    for (int m = 32; m; m >>= 1) ss += __shfl_xor(ss, m);

    __shared__ float red[2];
    __shared__ float nv[128];
    if ((d & 63) == 0) red[d >> 6] = ss;
    __syncthreads();
    float var = (red[0] + red[1]) * (1.0f / 128.0f);
    float nx = x * rsqrtf(var + 1e-6f) * knw[d];
    nv[d] = nx;
    __syncthreads();

    const float* pev = pe + ((size_t)b * SEQ + s) * HD;
    float o;
    if (d < 64) {
        o = nx * pev[d] - nv[d + 64] * pev[64 + d];
    } else {
        o = nv[d - 64] * pev[d] + nx * pev[d - 64];
    }
    buf[d] = (bf16)o;
}

// ---------------------------------------------------------------------------
// Flash attention, causal, GQA rep=2.  8 waves x 16 q-rows = 128 q rows per
// block; per-wave inner code identical to the verified r6 kernel (64-key
// tiles, static-max softmax, register prefetch, P overlay in Ks).  Fixed
// per-tile costs (3 barriers, staging instrs, prefetch addressing) amortize
// over 2x q-rows at the SAME 16 waves/CU (2 blocks x 8 waves, VGPR ~80).
// Ks stride 152 (2-way max banks) so the 8-wave P overlay (9216 elem) fits.
// Waves fully masked on a tail tile skip compute (wave-uniform branch).
// ---------------------------------------------------------------------------
__global__ __launch_bounds__(512) void fattn(bf16* __restrict__ O,
                                             const bf16* __restrict__ Q,
                                             const bf16* __restrict__ Kh,
                                             const bf16* __restrict__ Vtg,
                                             const float* __restrict__ pe,
                                             const float* __restrict__ qnw)
{
    const int h    = blockIdx.y;
    const int b    = blockIdx.z;
    const int qblk = (h & 8) ? (int)blockIdx.x
                             : ((int)gridDim.x - 1 - (int)blockIdx.x);
    const int kv   = h >> 1;

    const int tid  = threadIdx.x;
    const int wv   = tid >> 6;           // 0..7
    const int lane = tid & 63;
    const int quad = lane >> 4;
    const int c    = lane & 15;

    __shared__ bf16 Ks[64 * 152];        // [key][d] stride 152; low 9216 elems double as P
    __shared__ bf16 Vs[128 * 72];        // [d][key]

    const int qw = qblk * 128 + wv * 16;

    // ---- prologue: load raw q row, RMSNorm + RoPE in registers ----
    bf16x8 qf[4];
    {
        const bf16* qp = Q + (size_t)(b * SEQ + qw + c) * 2048 + h * HD + quad * 8;
        float qv[4][8];
        float ss = 0.0f;
        #pragma unroll
        for (int t = 0; t < 4; t++) {
            bf16x8 raw = *(const bf16x8*)(qp + t * 32);
            #pragma unroll
            for (int j = 0; j < 8; j++) { qv[t][j] = (float)raw[j]; ss += qv[t][j] * qv[t][j]; }
        }
        // lanes c, c+16, c+32, c+48 hold the same q row
        ss += __shfl_xor(ss, 16);
        ss += __shfl_xor(ss, 32);
        const float inv = rsqrtf(ss * (1.0f / 128.0f) + 1e-6f);
        const float* pev = pe + (size_t)(b * SEQ + qw + c) * HD + quad * 8;
        float nx[4][8], pv[4][8];
        #pragma unroll
        for (int t = 0; t < 4; t++)
            #pragma unroll
            for (int j = 0; j < 8; j++) {
                pv[t][j] = pev[t * 32 + j];
                nx[t][j] = qv[t][j] * inv * qnw[t * 32 + quad * 8 + j];
            }
        #pragma unroll
        for (int t = 0; t < 2; t++)
            #pragma unroll
            for (int j = 0; j < 8; j++) {
                qf[t][j]     = (bf16)(nx[t][j] * pv[t][j]     - nx[t + 2][j] * pv[t + 2][j]);
                qf[t + 2][j] = (bf16)(nx[t][j] * pv[t + 2][j] + nx[t + 2][j] * pv[t][j]);
            }
    }

    floatx4 o_acc[8] = {};
    float l_part[4] = {};

    const bf16* kbase = Kh  + (size_t)b * SEQ * 1024 + kv * HD;        // + s*1024
    const bf16* vbase = Vtg + ((size_t)b * 1024 + kv * HD) * 2048;     // + d*2048

    const int kr  = tid >> 3, ksc = (tid & 7) * 16;   // K staging: 64 rows x 128, 2 v8/thread
    const int vd  = tid >> 2, vkc = (tid & 3) * 16;   // V^T staging: 128 rows x 64, 2 v8/thread
    bf16* psw = &Ks[wv * 1152];                       // P overlay inside Ks
    const int nkt = 2 * qblk + 2;
    const float kS = 0.08838834764831845f * 1.4426950408889634f;  // scale*log2e
    const float kB = 11.5f * 1.4426950408889634f;                 // M*log2e

    // ---- load tile 0 into registers ----
    bf16x8 kreg[2], vreg[2];
    {
        const bf16* kp = kbase + (size_t)kr * 1024 + ksc;
        const bf16* vp = vbase + (size_t)vd * 2048 + vkc;
        kreg[0] = *(const bf16x8*)(kp);
        kreg[1] = *(const bf16x8*)(kp + 8);
        vreg[0] = *(const bf16x8*)(vp);
        vreg[1] = *(const bf16x8*)(vp + 8);
    }

    for (int kt = 0; kt < nkt; kt++) {
        const int k0 = kt * 64;
        // ---- commit prefetched tile to LDS ----
        *(bf16x8*)(&Ks[kr * 152 + ksc])     = kreg[0];
        *(bf16x8*)(&Ks[kr * 152 + ksc + 8]) = kreg[1];
        *(bf16x8*)(&Vs[vd * 72 + vkc])      = vreg[0];
        *(bf16x8*)(&Vs[vd * 72 + vkc + 8])  = vreg[1];
        __syncthreads();

        // ---- prefetch next tile (latency covered by compute below) ----
        if (kt + 1 < nkt) {
            const bf16* kp = kbase + (size_t)(k0 + 64 + kr) * 1024 + ksc;
            const bf16* vp = vbase + (size_t)vd * 2048 + (k0 + 64) + vkc;
            kreg[0] = *(const bf16x8*)(kp);
            kreg[1] = *(const bf16x8*)(kp + 8);
            vreg[0] = *(const bf16x8*)(vp);
            vreg[1] = *(const bf16x8*)(vp + 8);
        }

        // wave-uniform: does this wave have any unmasked key in this tile?
        const bool active = (k0 <= qw + 15);

        // ---- QK^T: 16 q-rows x 64 keys ----
        floatx4 sc[4] = {};
        if (active) {
            #pragma unroll
            for (int t = 0; t < 4; t++) {
                #pragma unroll
                for (int g = 0; g < 4; g++) {
                    bf16x8 kf = *(const bf16x8*)(&Ks[(g * 16 + c) * 152 + t * 32 + quad * 8]);
                    sc[g] = __builtin_amdgcn_mfma_f32_16x16x32_bf16(qf[t], kf, sc[g], 0, 0, 0);
                }
            }
        }

        // ---- raw barrier: all waves done reading Ks before P overlay writes.
        // No vmcnt drain (prefetch stays in flight). ----
        asm volatile("" ::: "memory");
        __builtin_amdgcn_s_barrier();
        asm volatile("" ::: "memory");

        if (active) {
            // ---- static-max softmax + P store (no reductions) ----
            const bool tail = (kt >= nkt - 2);
            #pragma unroll
            for (int r = 0; r < 4; r++) {
                const int qrow = qw + quad * 4 + r;
                #pragma unroll
                for (int g = 0; g < 4; g++) {
                    float p = exp2f(sc[g][r] * kS - kB);
                    if (tail && (k0 + g * 16 + c > qrow)) p = 0.0f;
                    l_part[r] += p;
                    psw[(quad * 4 + r) * 72 + g * 16 + c] = (bf16)p;
                }
            }
            // drain ds_writes before wave-local ds_reads (vmcnt untouched)
            asm volatile("s_waitcnt lgkmcnt(0)" ::: "memory");
            bf16x8 pf0 = *(const bf16x8*)(&psw[c * 72 + quad * 8]);
            bf16x8 pf1 = *(const bf16x8*)(&psw[c * 72 + 32 + quad * 8]);

            // ---- PV ----
            #pragma unroll
            for (int f = 0; f < 8; f++) {
                bf16x8 vf0 = *(const bf16x8*)(&Vs[(f * 16 + c) * 72 + quad * 8]);
                bf16x8 vf1 = *(const bf16x8*)(&Vs[(f * 16 + c) * 72 + 32 + quad * 8]);
                o_acc[f] = __builtin_amdgcn_mfma_f32_16x16x32_bf16(pf0, vf0, o_acc[f], 0, 0, 0);
                o_acc[f] = __builtin_amdgcn_mfma_f32_16x16x32_bf16(pf1, vf1, o_acc[f], 0, 0, 0);
            }
        }
        __syncthreads();
    }

    // ---- epilogue: one l-reduction per row, normalize, store ----
    #pragma unroll
    for (int r = 0; r < 4; r++) {
        float l = l_part[r];
        #pragma unroll
        for (int msk = 8; msk; msk >>= 1) l += __shfl_xor(l, msk);
        const float inv = 1.0f / l;
        bf16* op = O + (size_t)(b * SEQ + qw + quad * 4 + r) * 2048 + h * HD;
        #pragma unroll
        for (int f = 0; f < 8; f++) op[f * 16 + c] = (bf16)(o_acc[f][r] * inv);
    }
}

// ---------------------------------------------------------------------------
extern "C" void kernel_launch(void* const* d_in, const int* in_sizes, int n_in,
                              void* d_out, int out_size, void* d_ws, size_t ws_size,
                              hipStream_t stream)
{
    const float* x   = (const float*)d_in[0];
    const float* pe  = (const float*)d_in[1];
    const float* qw  = (const float*)d_in[2];
    const float* kw  = (const float*)d_in[3];
    const float* vw  = (const float*)d_in[4];
    const float* ow  = (const float*)d_in[5];
    const float* qnw = (const float*)d_in[6];
    const float* knw = (const float*)d_in[7];
    float* out = (float*)d_out;

    bf16* qb = (bf16*)d_ws;          // [B][S][2048]   row-major (raw q)
    bf16* kb = qb + XN;              // [B][S][1024]   row-major
    bf16* vt = kb + KWN * 2;         // [B][1024][2048] V^T
    bf16* ab = vt + VWN * 2;         // [B][S][2048]   row-major
    bf16* cvt_base = ab + XN;

    const bool fit = ws_size >= (size_t)92274688;
    const int M = BATCH * SEQ;

    if (fit) {
        bf16* xb  = cvt_base;
        bf16* qwb = xb  + XN;
        bf16* owb = qwb + QWN + KWN + VWN;

        cvt_all<<<10240, 256, 0, stream>>>(xb, x, qw, kw, vw, ow);

        gemm128<1, 1, 3><<<dim3(32, 32), 256, 0, stream>>>(qb, xb, qwb, M, 4096, 2048);

        norm_rope_k<<<dim3(SEQ, NKV, BATCH), 128, 0, stream>>>(kb, pe, knw);
        fattn<<<dim3(SEQ / 128, NH, BATCH), 512, 0, stream>>>(ab, qb, kb, vt, pe, qnw);

        gemm128<1, 1, 0><<<dim3(32, 16), 256, 0, stream>>>(out, ab, owb, M, 2048, 2048);
    } else {
        gemm128<0, 0, 1><<<dim3(32, 16), 256, 0, stream>>>(qb, x, qw, M, 2048, 2048);
        gemm128<0, 0, 1><<<dim3(32,  8), 256, 0, stream>>>(kb, x, kw, M, 1024, 2048);
        gemm128<0, 0, 2><<<dim3(32,  8), 256, 0, stream>>>(vt, x, vw, M, 1024, 2048);

        norm_rope_k<<<dim3(SEQ, NKV, BATCH), 128, 0, stream>>>(kb, pe, knw);
        fattn<<<dim3(SEQ / 128, NH, BATCH), 512, 0, stream>>>(ab, qb, kb, vt, pe, qnw);

        gemm128<0, 0, 0><<<dim3(32, 16), 256, 0, stream>>>(out, ab, ow, M, 2048, 2048);
    }
}

// Round 8
// 373.054 us; speedup vs baseline: 1.1805x; 1.0673x over previous
//
#include <hip/hip_runtime.h>
#include <hip/hip_bf16.h>

#define BATCH 2
#define SEQ   2048
#define HID   2048
#define NH    16
#define NKV   8
#define HD    128

typedef __bf16 bf16;
typedef bf16  bf16x8  __attribute__((ext_vector_type(8)));
typedef bf16  bf16x4  __attribute__((ext_vector_type(4)));
typedef float floatx4 __attribute__((ext_vector_type(4)));

typedef __attribute__((address_space(3))) void lds_void;
typedef const __attribute__((address_space(1))) void gmem_void;

__device__ inline void async16(const void* g, void* l) {
    __builtin_amdgcn_global_load_lds((gmem_void*)g, (lds_void*)l, 16, 0, 0);
}

// workspace layout constants (elements)
#define XN  8388608u
#define QWN 4194304u
#define KWN 2097152u
#define VWN 2097152u
#define OWN 4194304u

// ---------------------------------------------------------------------------
// Fused f32 -> bf16 convert for x + all four weights in ONE launch.
// ---------------------------------------------------------------------------
__global__ __launch_bounds__(256) void cvt_all(bf16* __restrict__ dst,
                                               const float* __restrict__ x,
                                               const float* __restrict__ qw,
                                               const float* __restrict__ kw,
                                               const float* __restrict__ vw,
                                               const float* __restrict__ ow)
{
    const int blk = blockIdx.x;
    const float* src;
    size_t off;
    if (blk < 4096)      { src = x;  off = (size_t)blk * 2048; }
    else if (blk < 6144) { src = qw; off = (size_t)(blk - 4096) * 2048; }
    else if (blk < 7168) { src = kw; off = (size_t)(blk - 6144) * 2048; }
    else if (blk < 8192) { src = vw; off = (size_t)(blk - 7168) * 2048; }
    else                 { src = ow; off = (size_t)(blk - 8192) * 2048; }

    const int t = threadIdx.x * 8;
    const float4* p = (const float4*)(src + off + t);
    float4 u0 = p[0], u1 = p[1];
    bf16x8 v;
    v[0] = (bf16)u0.x; v[1] = (bf16)u0.y; v[2] = (bf16)u0.z; v[3] = (bf16)u0.w;
    v[4] = (bf16)u1.x; v[5] = (bf16)u1.y; v[6] = (bf16)u1.z; v[7] = (bf16)u1.w;
    *(bf16x8*)(dst + (size_t)blk * 2048 + t) = v;
}

// ---------------------------------------------------------------------------
// GEMM  C = A[M,K] * W[N,K]^T, 128x128 tile, BK=64.
// XCD-aware bijective block swizzle (T1): each XCD's L2 holds a contiguous
// chunk of tile space (W-panel reuse).  Requires nwg % 8 == 0 (all our
// launches: 1024 / 512 / 256); falls back to identity otherwise.
// ---------------------------------------------------------------------------
template <int AMODE, int WMODE, int CMODE>
__global__ __launch_bounds__(256) void gemm128(void* __restrict__ Cp,
                                               const void* __restrict__ Ap,
                                               const void* __restrict__ Wp,
                                               int M, int N, int K)
{
    __shared__ bf16 As[128 * 64];
    __shared__ bf16 Ws[128 * 64];

    const int tid  = threadIdx.x;
    const int wv   = tid >> 6;
    const int lane = tid & 63;
    const int quad = lane >> 4;
    const int c    = lane & 15;

    const int nwg = gridDim.x * gridDim.y;
    int bx = blockIdx.x, by = blockIdx.y;
    if ((nwg & 7) == 0) {
        int lin = by * gridDim.x + bx;
        lin = (lin & 7) * (nwg >> 3) + (lin >> 3);
        bx = lin % gridDim.x;
        by = lin / gridDim.x;
    }
    const int m0 = bx * 128;
    const int n0 = by * 128;
    const int wm = (wv >> 1) * 64;
    const int wn = (wv & 1) * 64;

    const int arow = lane >> 3;
    const int acol = (lane & 7) * 8;

    floatx4 acc[4][4] = {};

    for (int k0 = 0; k0 < K; k0 += 64) {
        if constexpr (AMODE == 0) {
            const float* A = (const float*)Ap;
            #pragma unroll
            for (int it = 0; it < 4; it++) {
                int row = it * 32 + (tid >> 3);
                int col = (tid & 7) * 8;
                const float4* p = (const float4*)(A + (size_t)(m0 + row) * K + k0 + col);
                float4 u0 = p[0], u1 = p[1];
                bf16x8 v;
                v[0] = (bf16)u0.x; v[1] = (bf16)u0.y; v[2] = (bf16)u0.z; v[3] = (bf16)u0.w;
                v[4] = (bf16)u1.x; v[5] = (bf16)u1.y; v[6] = (bf16)u1.z; v[7] = (bf16)u1.w;
                *(bf16x8*)(&As[row * 64 + col]) = v;
            }
        } else {
            const bf16* A = (const bf16*)Ap;
            #pragma unroll
            for (int ch = 0; ch < 4; ch++) {
                int row = wv * 32 + ch * 8 + arow;
                async16(A + (size_t)(m0 + row) * K + k0 + acol,
                        &As[(wv * 32 + ch * 8) * 64]);
            }
        }
        if constexpr (WMODE == 0) {
            const float* W = (const float*)Wp;
            #pragma unroll
            for (int it = 0; it < 4; it++) {
                int row = it * 32 + (tid >> 3);
                int col = (tid & 7) * 8;
                const float4* p = (const float4*)(W + (size_t)(n0 + row) * K + k0 + col);
                float4 u0 = p[0], u1 = p[1];
                bf16x8 v;
                v[0] = (bf16)u0.x; v[1] = (bf16)u0.y; v[2] = (bf16)u0.z; v[3] = (bf16)u0.w;
                v[4] = (bf16)u1.x; v[5] = (bf16)u1.y; v[6] = (bf16)u1.z; v[7] = (bf16)u1.w;
                *(bf16x8*)(&Ws[row * 64 + col]) = v;
            }
        } else {
            const bf16* W = (const bf16*)Wp;
            #pragma unroll
            for (int ch = 0; ch < 4; ch++) {
                int row = wv * 32 + ch * 8 + arow;
                async16(W + (size_t)(n0 + row) * K + k0 + acol,
                        &Ws[(wv * 32 + ch * 8) * 64]);
            }
        }
        __syncthreads();

        #pragma unroll
        for (int t = 0; t < 2; t++) {
            bf16x8 af[4], bw[4];
            #pragma unroll
            for (int i = 0; i < 4; i++)
                af[i] = *(const bf16x8*)(&As[(wm + i * 16 + c) * 64 + t * 32 + quad * 8]);
            #pragma unroll
            for (int j = 0; j < 4; j++)
                bw[j] = *(const bf16x8*)(&Ws[(wn + j * 16 + c) * 64 + t * 32 + quad * 8]);
            #pragma unroll
            for (int i = 0; i < 4; i++)
                #pragma unroll
                for (int j = 0; j < 4; j++)
                    acc[i][j] = __builtin_amdgcn_mfma_f32_16x16x32_bf16(af[i], bw[j], acc[i][j], 0, 0, 0);
        }
        __syncthreads();
    }

    if constexpr (CMODE == 0) {
        float* C = (float*)Cp;
        #pragma unroll
        for (int i = 0; i < 4; i++)
            #pragma unroll
            for (int j = 0; j < 4; j++)
                #pragma unroll
                for (int r = 0; r < 4; r++) {
                    int m = m0 + wm + i * 16 + quad * 4 + r;
                    int n = n0 + wn + j * 16 + c;
                    C[(size_t)m * N + n] = acc[i][j][r];
                }
    } else if constexpr (CMODE == 1) {
        bf16* C = (bf16*)Cp;
        #pragma unroll
        for (int i = 0; i < 4; i++)
            #pragma unroll
            for (int j = 0; j < 4; j++)
                #pragma unroll
                for (int r = 0; r < 4; r++) {
                    int m = m0 + wm + i * 16 + quad * 4 + r;
                    int n = n0 + wn + j * 16 + c;
                    C[(size_t)m * N + n] = (bf16)acc[i][j][r];
                }
    } else if constexpr (CMODE == 2) {
        bf16* C = (bf16*)Cp;
        const int b = m0 >> 11;
        #pragma unroll
        for (int j = 0; j < 4; j++) {
            int n = n0 + wn + j * 16 + c;
            size_t base = ((size_t)b * N + n) * 2048;
            #pragma unroll
            for (int i = 0; i < 4; i++) {
                int s0 = (m0 & 2047) + wm + i * 16 + quad * 4;
                bf16x4 v;
                #pragma unroll
                for (int r = 0; r < 4; r++) v[r] = (bf16)acc[i][j][r];
                *(bf16x4*)(&C[base + s0]) = v;
            }
        }
    } else {
        bf16* Cq = (bf16*)Cp;
        if (n0 < 2048) {
            #pragma unroll
            for (int i = 0; i < 4; i++)
                #pragma unroll
                for (int j = 0; j < 4; j++)
                    #pragma unroll
                    for (int r = 0; r < 4; r++) {
                        int m = m0 + wm + i * 16 + quad * 4 + r;
                        int n = n0 + wn + j * 16 + c;
                        Cq[(size_t)m * 2048 + n] = (bf16)acc[i][j][r];
                    }
        } else if (n0 < 3072) {
            bf16* Ck = Cq + XN;
            #pragma unroll
            for (int i = 0; i < 4; i++)
                #pragma unroll
                for (int j = 0; j < 4; j++)
                    #pragma unroll
                    for (int r = 0; r < 4; r++) {
                        int m = m0 + wm + i * 16 + quad * 4 + r;
                        int n = n0 - 2048 + wn + j * 16 + c;
                        Ck[(size_t)m * 1024 + n] = (bf16)acc[i][j][r];
                    }
        } else {
            bf16* Cv = Cq + XN + QWN;
            const int b = m0 >> 11;
            #pragma unroll
            for (int j = 0; j < 4; j++) {
                int n = n0 - 3072 + wn + j * 16 + c;
                size_t base = ((size_t)b * 1024 + n) * 2048;
                #pragma unroll
                for (int i = 0; i < 4; i++) {
                    int s0 = (m0 & 2047) + wm + i * 16 + quad * 4;
                    bf16x4 v;
                    #pragma unroll
                    for (int r = 0; r < 4; r++) v[r] = (bf16)acc[i][j][r];
                    *(bf16x4*)(&Cv[base + s0]) = v;
                }
            }
        }
    }
}

// ---------------------------------------------------------------------------
// RMSNorm(D=128) + RoPE for K ONLY.
// ---------------------------------------------------------------------------
__global__ __launch_bounds__(128) void norm_rope_k(bf16* __restrict__ k,
                                                   const float* __restrict__ pe,
                                                   const float* __restrict__ knw)
{
    const int s  = blockIdx.x;
    const int hh = blockIdx.y;
    const int b  = blockIdx.z;
    const int d  = threadIdx.x;

    bf16* buf = k + (size_t)(b * SEQ + s) * 1024 + hh * HD;

    float x = (float)buf[d];
    float ss = x * x;
    #pragma unroll
    for (int m = 32; m; m >>= 1) ss += __shfl_xor(ss, m);

    __shared__ float red[2];
    __shared__ float nv[128];
    if ((d & 63) == 0) red[d >> 6] = ss;
    __syncthreads();
    float var = (red[0] + red[1]) * (1.0f / 128.0f);
    float nx = x * rsqrtf(var + 1e-6f) * knw[d];
    nv[d] = nx;
    __syncthreads();

    const float* pev = pe + ((size_t)b * SEQ + s) * HD;
    float o;
    if (d < 64) {
        o = nx * pev[d] - nv[d + 64] * pev[64 + d];
    } else {
        o = nv[d - 64] * pev[d] + nx * pev[d - 64];
    }
    buf[d] = (bf16)o;
}

// ---------------------------------------------------------------------------
// Flash attention, causal, GQA rep=2.  8 waves x 16 q-rows = 128 q rows per
// block; per-wave inner code = verified r0 structure (64-key tiles,
// static-max softmax, register prefetch, P via separate per-wave LDS,
// 2 barriers/tile).  Grid (SEQ/128, BATCH, NH): CU hosts blocks i and
// i+256 which differ by h->h+8, so the (h&8) qblk flip pairs complementary
// causal workloads -> every CU gets 34 tiles total (balanced).  LDS 54 KB,
// 2 blocks/CU (grid-capped), 16 waves/CU.
// ---------------------------------------------------------------------------
__global__ __launch_bounds__(512) void fattn(bf16* __restrict__ O,
                                             const bf16* __restrict__ Q,
                                             const bf16* __restrict__ Kh,
                                             const bf16* __restrict__ Vtg,
                                             const float* __restrict__ pe,
                                             const float* __restrict__ qnw)
{
    const int h    = blockIdx.z;
    const int b    = blockIdx.y;
    const int qblk = (h & 8) ? (int)blockIdx.x
                             : ((int)gridDim.x - 1 - (int)blockIdx.x);
    const int kv   = h >> 1;

    const int tid  = threadIdx.x;
    const int wv   = tid >> 6;           // 0..7
    const int lane = tid & 63;
    const int quad = lane >> 4;
    const int c    = lane & 15;

    __shared__ bf16 Ks[64 * 136];        // [key][d]
    __shared__ bf16 Vs[128 * 72];        // [d][key]
    __shared__ bf16 Ps[8 * 16 * 72];     // per-wave P tile

    const int qw = qblk * 128 + wv * 16;

    // ---- prologue: load raw q row, RMSNorm + RoPE in registers ----
    bf16x8 qf[4];
    {
        const bf16* qp = Q + (size_t)(b * SEQ + qw + c) * 2048 + h * HD + quad * 8;
        float qv[4][8];
        float ss = 0.0f;
        #pragma unroll
        for (int t = 0; t < 4; t++) {
            bf16x8 raw = *(const bf16x8*)(qp + t * 32);
            #pragma unroll
            for (int j = 0; j < 8; j++) { qv[t][j] = (float)raw[j]; ss += qv[t][j] * qv[t][j]; }
        }
        // lanes c, c+16, c+32, c+48 hold the same q row
        ss += __shfl_xor(ss, 16);
        ss += __shfl_xor(ss, 32);
        const float inv = rsqrtf(ss * (1.0f / 128.0f) + 1e-6f);
        const float* pev = pe + (size_t)(b * SEQ + qw + c) * HD + quad * 8;
        float nx[4][8], pv[4][8];
        #pragma unroll
        for (int t = 0; t < 4; t++)
            #pragma unroll
            for (int j = 0; j < 8; j++) {
                pv[t][j] = pev[t * 32 + j];
                nx[t][j] = qv[t][j] * inv * qnw[t * 32 + quad * 8 + j];
            }
        #pragma unroll
        for (int t = 0; t < 2; t++)
            #pragma unroll
            for (int j = 0; j < 8; j++) {
                qf[t][j]     = (bf16)(nx[t][j] * pv[t][j]     - nx[t + 2][j] * pv[t + 2][j]);
                qf[t + 2][j] = (bf16)(nx[t][j] * pv[t + 2][j] + nx[t + 2][j] * pv[t][j]);
            }
    }

    floatx4 o_acc[8] = {};
    float l_part[4] = {};

    const bf16* kbase = Kh  + (size_t)b * SEQ * 1024 + kv * HD;        // + s*1024
    const bf16* vbase = Vtg + ((size_t)b * 1024 + kv * HD) * 2048;     // + d*2048

    const int kr  = tid >> 3, ksc = (tid & 7) * 16;   // K staging: 64 rows x 128, 2 v8/thread
    const int vd  = tid >> 2, vkc = (tid & 3) * 16;   // V^T staging: 128 rows x 64, 2 v8/thread
    bf16* psw = &Ps[wv * 16 * 72];
    const int nkt = 2 * qblk + 2;
    const float kS = 0.08838834764831845f * 1.4426950408889634f;  // scale*log2e
    const float kB = 11.5f * 1.4426950408889634f;                 // M*log2e

    // ---- load tile 0 into registers ----
    bf16x8 kreg[2], vreg[2];
    {
        const bf16* kp = kbase + (size_t)kr * 1024 + ksc;
        const bf16* vp = vbase + (size_t)vd * 2048 + vkc;
        kreg[0] = *(const bf16x8*)(kp);
        kreg[1] = *(const bf16x8*)(kp + 8);
        vreg[0] = *(const bf16x8*)(vp);
        vreg[1] = *(const bf16x8*)(vp + 8);
    }

    for (int kt = 0; kt < nkt; kt++) {
        const int k0 = kt * 64;
        // ---- commit prefetched tile to LDS ----
        *(bf16x8*)(&Ks[kr * 136 + ksc])     = kreg[0];
        *(bf16x8*)(&Ks[kr * 136 + ksc + 8]) = kreg[1];
        *(bf16x8*)(&Vs[vd * 72 + vkc])      = vreg[0];
        *(bf16x8*)(&Vs[vd * 72 + vkc + 8])  = vreg[1];
        __syncthreads();

        // ---- prefetch next tile (latency covered by compute below) ----
        if (kt + 1 < nkt) {
            const bf16* kp = kbase + (size_t)(k0 + 64 + kr) * 1024 + ksc;
            const bf16* vp = vbase + (size_t)vd * 2048 + (k0 + 64) + vkc;
            kreg[0] = *(const bf16x8*)(kp);
            kreg[1] = *(const bf16x8*)(kp + 8);
            vreg[0] = *(const bf16x8*)(vp);
            vreg[1] = *(const bf16x8*)(vp + 8);
        }

        // wave-uniform: does this wave have any unmasked key in this tile?
        if (k0 <= qw + 15) {
            // ---- QK^T: 16 q-rows x 64 keys ----
            floatx4 sc[4] = {};
            #pragma unroll
            for (int t = 0; t < 4; t++) {
                #pragma unroll
                for (int g = 0; g < 4; g++) {
                    bf16x8 kf = *(const bf16x8*)(&Ks[(g * 16 + c) * 136 + t * 32 + quad * 8]);
                    sc[g] = __builtin_amdgcn_mfma_f32_16x16x32_bf16(qf[t], kf, sc[g], 0, 0, 0);
                }
            }

            // ---- static-max softmax + P store (no reductions) ----
            const bool tail = (kt >= nkt - 2);
            #pragma unroll
            for (int r = 0; r < 4; r++) {
                const int qrow = qw + quad * 4 + r;
                #pragma unroll
                for (int g = 0; g < 4; g++) {
                    float p = exp2f(sc[g][r] * kS - kB);
                    if (tail && (k0 + g * 16 + c > qrow)) p = 0.0f;
                    l_part[r] += p;
                    psw[(quad * 4 + r) * 72 + g * 16 + c] = (bf16)p;
                }
            }
            // drain ds_writes before wave-local ds_reads (vmcnt untouched)
            asm volatile("s_waitcnt lgkmcnt(0)" ::: "memory");
            bf16x8 pf0 = *(const bf16x8*)(&psw[c * 72 + quad * 8]);
            bf16x8 pf1 = *(const bf16x8*)(&psw[c * 72 + 32 + quad * 8]);

            // ---- PV ----
            #pragma unroll
            for (int f = 0; f < 8; f++) {
                bf16x8 vf0 = *(const bf16x8*)(&Vs[(f * 16 + c) * 72 + quad * 8]);
                bf16x8 vf1 = *(const bf16x8*)(&Vs[(f * 16 + c) * 72 + 32 + quad * 8]);
                o_acc[f] = __builtin_amdgcn_mfma_f32_16x16x32_bf16(pf0, vf0, o_acc[f], 0, 0, 0);
                o_acc[f] = __builtin_amdgcn_mfma_f32_16x16x32_bf16(pf1, vf1, o_acc[f], 0, 0, 0);
            }
        }
        __syncthreads();
    }

    // ---- epilogue: one l-reduction per row, normalize, store ----
    #pragma unroll
    for (int r = 0; r < 4; r++) {
        float l = l_part[r];
        #pragma unroll
        for (int msk = 8; msk; msk >>= 1) l += __shfl_xor(l, msk);
        const float inv = 1.0f / l;
        bf16* op = O + (size_t)(b * SEQ + qw + quad * 4 + r) * 2048 + h * HD;
        #pragma unroll
        for (int f = 0; f < 8; f++) op[f * 16 + c] = (bf16)(o_acc[f][r] * inv);
    }
}

// ---------------------------------------------------------------------------
extern "C" void kernel_launch(void* const* d_in, const int* in_sizes, int n_in,
                              void* d_out, int out_size, void* d_ws, size_t ws_size,
                              hipStream_t stream)
{
    const float* x   = (const float*)d_in[0];
    const float* pe  = (const float*)d_in[1];
    const float* qw  = (const float*)d_in[2];
    const float* kw  = (const float*)d_in[3];
    const float* vw  = (const float*)d_in[4];
    const float* ow  = (const float*)d_in[5];
    const float* qnw = (const float*)d_in[6];
    const float* knw = (const float*)d_in[7];
    float* out = (float*)d_out;

    bf16* qb = (bf16*)d_ws;          // [B][S][2048]   row-major (raw q)
    bf16* kb = qb + XN;              // [B][S][1024]   row-major
    bf16* vt = kb + KWN * 2;         // [B][1024][2048] V^T
    bf16* ab = vt + VWN * 2;         // [B][S][2048]   row-major
    bf16* cvt_base = ab + XN;

    const bool fit = ws_size >= (size_t)92274688;
    const int M = BATCH * SEQ;

    if (fit) {
        bf16* xb  = cvt_base;
        bf16* qwb = xb  + XN;
        bf16* owb = qwb + QWN + KWN + VWN;

        cvt_all<<<10240, 256, 0, stream>>>(xb, x, qw, kw, vw, ow);

        gemm128<1, 1, 3><<<dim3(32, 32), 256, 0, stream>>>(qb, xb, qwb, M, 4096, 2048);

        norm_rope_k<<<dim3(SEQ, NKV, BATCH), 128, 0, stream>>>(kb, pe, knw);
        fattn<<<dim3(SEQ / 128, BATCH, NH), 512, 0, stream>>>(ab, qb, kb, vt, pe, qnw);

        gemm128<1, 1, 0><<<dim3(32, 16), 256, 0, stream>>>(out, ab, owb, M, 2048, 2048);
    } else {
        gemm128<0, 0, 1><<<dim3(32, 16), 256, 0, stream>>>(qb, x, qw, M, 2048, 2048);
        gemm128<0, 0, 1><<<dim3(32,  8), 256, 0, stream>>>(kb, x, kw, M, 1024, 2048);
        gemm128<0, 0, 2><<<dim3(32,  8), 256, 0, stream>>>(vt, x, vw, M, 1024, 2048);

        norm_rope_k<<<dim3(SEQ, NKV, BATCH), 128, 0, stream>>>(kb, pe, knw);
        fattn<<<dim3(SEQ / 128, BATCH, NH), 512, 0, stream>>>(ab, qb, kb, vt, pe, qnw);

        gemm128<0, 0, 0><<<dim3(32, 16), 256, 0, stream>>>(out, ab, ow, M, 2048, 2048);
    }
}

// Round 9
// 359.355 us; speedup vs baseline: 1.2255x; 1.0381x over previous
//
#include <hip/hip_runtime.h>
#include <hip/hip_bf16.h>

#define BATCH 2
#define SEQ   2048
#define HID   2048
#define NH    16
#define NKV   8
#define HD    128

typedef __bf16 bf16;
typedef bf16  bf16x8  __attribute__((ext_vector_type(8)));
typedef bf16  bf16x4  __attribute__((ext_vector_type(4)));
typedef float floatx4 __attribute__((ext_vector_type(4)));

typedef __attribute__((address_space(3))) void lds_void;
typedef const __attribute__((address_space(1))) void gmem_void;

__device__ inline void async16(const void* g, void* l) {
    __builtin_amdgcn_global_load_lds((gmem_void*)g, (lds_void*)l, 16, 0, 0);
}

// workspace layout constants (elements)
#define XN  8388608u
#define QWN 4194304u
#define KWN 2097152u
#define VWN 2097152u
#define OWN 4194304u

// ---------------------------------------------------------------------------
// Fused f32 -> bf16 convert for x + all four weights in ONE launch.
// ---------------------------------------------------------------------------
__global__ __launch_bounds__(256) void cvt_all(bf16* __restrict__ dst,
                                               const float* __restrict__ x,
                                               const float* __restrict__ qw,
                                               const float* __restrict__ kw,
                                               const float* __restrict__ vw,
                                               const float* __restrict__ ow)
{
    const int blk = blockIdx.x;
    const float* src;
    size_t off;
    if (blk < 4096)      { src = x;  off = (size_t)blk * 2048; }
    else if (blk < 6144) { src = qw; off = (size_t)(blk - 4096) * 2048; }
    else if (blk < 7168) { src = kw; off = (size_t)(blk - 6144) * 2048; }
    else if (blk < 8192) { src = vw; off = (size_t)(blk - 7168) * 2048; }
    else                 { src = ow; off = (size_t)(blk - 8192) * 2048; }

    const int t = threadIdx.x * 8;
    const float4* p = (const float4*)(src + off + t);
    float4 u0 = p[0], u1 = p[1];
    bf16x8 v;
    v[0] = (bf16)u0.x; v[1] = (bf16)u0.y; v[2] = (bf16)u0.z; v[3] = (bf16)u0.w;
    v[4] = (bf16)u1.x; v[5] = (bf16)u1.y; v[6] = (bf16)u1.z; v[7] = (bf16)u1.w;
    *(bf16x8*)(dst + (size_t)blk * 2048 + t) = v;
}

// ---------------------------------------------------------------------------
// Fused QKV projection GEMM, 256x256 tile, BK=64, 8 waves, double-buffered
// LDS (128 KB), ONE barrier per K-tile.  Staging for tile t+1 is issued
// right after the barrier into the idle buffer; the 64-MFMA compute of tile
// t provides ~620 cycles of cover before the next barrier's vmcnt drain --
// the m97-structure's per-32-MFMA drain stall amortizes 4x.
// A[4096][2048] bf16, W[4096][2048] bf16 (q|k|v rows), epilogue = fused
// QKV split (q row-major | k row-major | v transposed).
// ---------------------------------------------------------------------------
__global__ __launch_bounds__(512) void gemm256_qkv(bf16* __restrict__ Cq,
                                                   const bf16* __restrict__ A,
                                                   const bf16* __restrict__ W)
{
    __shared__ bf16 As[2 * 256 * 64];   // 64 KB
    __shared__ bf16 Ws[2 * 256 * 64];   // 64 KB

    const int tid  = threadIdx.x;
    const int wv   = tid >> 6;           // 0..7
    const int lane = tid & 63;
    const int quad = lane >> 4;
    const int c    = lane & 15;

    // XCD-aware bijective swizzle over 256 blocks: XCD x gets lin2 in
    // [x*32, x*32+32) -> 2 W-panels per XCD, 16x L2 reuse each.
    int lin = blockIdx.y * gridDim.x + blockIdx.x;
    lin = (lin & 7) * 32 + (lin >> 3);
    const int m0 = (lin & 15) * 256;
    const int n0 = (lin >> 4) * 256;

    const int wm = (wv >> 2) * 128;      // 0 / 128
    const int wn = (wv & 3) * 64;        // 0 / 64 / 128 / 192

    const int srow = tid >> 3;           // 0..63
    const int scol = (tid & 7) * 8;      // 0..56

    constexpr int K  = 2048;
    constexpr int NT = K / 64;

    floatx4 acc[8][4] = {};

    auto stage = [&](int kt, int sel) {
        const size_t ko = (size_t)kt * 64;
        bf16* Ab = &As[sel * 16384];
        bf16* Wb = &Ws[sel * 16384];
        #pragma unroll
        for (int l = 0; l < 4; ++l)
            async16(A + (size_t)(m0 + l * 64 + srow) * K + ko + scol,
                    Ab + l * 4096 + wv * 512);
        #pragma unroll
        for (int l = 0; l < 4; ++l)
            async16(W + (size_t)(n0 + l * 64 + srow) * K + ko + scol,
                    Wb + l * 4096 + wv * 512);
    };

    stage(0, 0);

    int sel = 0;
    for (int t = 0; t < NT; ++t) {
        __syncthreads();                 // drain vmcnt (tile t landed, all waves)
        if (t + 1 < NT) stage(t + 1, sel ^ 1);

        const bf16* Ab = &As[sel * 16384];
        const bf16* Wb = &Ws[sel * 16384];
        #pragma unroll
        for (int ks = 0; ks < 2; ++ks) {
            bf16x8 af[8], bw[4];
            #pragma unroll
            for (int i = 0; i < 8; i++)
                af[i] = *(const bf16x8*)(Ab + (wm + i * 16 + c) * 64 + ks * 32 + quad * 8);
            #pragma unroll
            for (int j = 0; j < 4; j++)
                bw[j] = *(const bf16x8*)(Wb + (wn + j * 16 + c) * 64 + ks * 32 + quad * 8);
            __builtin_amdgcn_s_setprio(1);
            #pragma unroll
            for (int i = 0; i < 8; i++)
                #pragma unroll
                for (int j = 0; j < 4; j++)
                    acc[i][j] = __builtin_amdgcn_mfma_f32_16x16x32_bf16(af[i], bw[j], acc[i][j], 0, 0, 0);
            __builtin_amdgcn_s_setprio(0);
        }
        sel ^= 1;
    }

    // ---- epilogue: fused QKV split (q | k | v^T) ----
    const int b = m0 >> 11;
    if (n0 < 2048) {
        #pragma unroll
        for (int i = 0; i < 8; i++)
            #pragma unroll
            for (int j = 0; j < 4; j++)
                #pragma unroll
                for (int r = 0; r < 4; r++) {
                    int m = m0 + wm + i * 16 + quad * 4 + r;
                    int n = n0 + wn + j * 16 + c;
                    Cq[(size_t)m * 2048 + n] = (bf16)acc[i][j][r];
                }
    } else if (n0 < 3072) {
        bf16* Ck = Cq + XN;
        #pragma unroll
        for (int i = 0; i < 8; i++)
            #pragma unroll
            for (int j = 0; j < 4; j++)
                #pragma unroll
                for (int r = 0; r < 4; r++) {
                    int m = m0 + wm + i * 16 + quad * 4 + r;
                    int n = n0 - 2048 + wn + j * 16 + c;
                    Ck[(size_t)m * 1024 + n] = (bf16)acc[i][j][r];
                }
    } else {
        bf16* Cv = Cq + XN + QWN;
        #pragma unroll
        for (int j = 0; j < 4; j++) {
            int n = n0 - 3072 + wn + j * 16 + c;
            size_t base = ((size_t)b * 1024 + n) * 2048;
            #pragma unroll
            for (int i = 0; i < 8; i++) {
                int s0 = (m0 & 2047) + wm + i * 16 + quad * 4;
                bf16x4 v;
                #pragma unroll
                for (int r = 0; r < 4; r++) v[r] = (bf16)acc[i][j][r];
                *(bf16x4*)(&Cv[base + s0]) = v;
            }
        }
    }
}

// ---------------------------------------------------------------------------
// GEMM  C = A[M,K] * W[N,K]^T, 128x128 tile, BK=64.  (fallback + O-proj)
// ---------------------------------------------------------------------------
template <int AMODE, int WMODE, int CMODE>
__global__ __launch_bounds__(256) void gemm128(void* __restrict__ Cp,
                                               const void* __restrict__ Ap,
                                               const void* __restrict__ Wp,
                                               int M, int N, int K)
{
    __shared__ bf16 As[128 * 64];
    __shared__ bf16 Ws[128 * 64];

    const int tid  = threadIdx.x;
    const int wv   = tid >> 6;
    const int lane = tid & 63;
    const int quad = lane >> 4;
    const int c    = lane & 15;

    const int nwg = gridDim.x * gridDim.y;
    int bx = blockIdx.x, by = blockIdx.y;
    if ((nwg & 7) == 0) {
        int lin = by * gridDim.x + bx;
        lin = (lin & 7) * (nwg >> 3) + (lin >> 3);
        bx = lin % gridDim.x;
        by = lin / gridDim.x;
    }
    const int m0 = bx * 128;
    const int n0 = by * 128;
    const int wm = (wv >> 1) * 64;
    const int wn = (wv & 1) * 64;

    const int arow = lane >> 3;
    const int acol = (lane & 7) * 8;

    floatx4 acc[4][4] = {};

    for (int k0 = 0; k0 < K; k0 += 64) {
        if constexpr (AMODE == 0) {
            const float* A = (const float*)Ap;
            #pragma unroll
            for (int it = 0; it < 4; it++) {
                int row = it * 32 + (tid >> 3);
                int col = (tid & 7) * 8;
                const float4* p = (const float4*)(A + (size_t)(m0 + row) * K + k0 + col);
                float4 u0 = p[0], u1 = p[1];
                bf16x8 v;
                v[0] = (bf16)u0.x; v[1] = (bf16)u0.y; v[2] = (bf16)u0.z; v[3] = (bf16)u0.w;
                v[4] = (bf16)u1.x; v[5] = (bf16)u1.y; v[6] = (bf16)u1.z; v[7] = (bf16)u1.w;
                *(bf16x8*)(&As[row * 64 + col]) = v;
            }
        } else {
            const bf16* A = (const bf16*)Ap;
            #pragma unroll
            for (int ch = 0; ch < 4; ch++) {
                int row = wv * 32 + ch * 8 + arow;
                async16(A + (size_t)(m0 + row) * K + k0 + acol,
                        &As[(wv * 32 + ch * 8) * 64]);
            }
        }
        if constexpr (WMODE == 0) {
            const float* W = (const float*)Wp;
            #pragma unroll
            for (int it = 0; it < 4; it++) {
                int row = it * 32 + (tid >> 3);
                int col = (tid & 7) * 8;
                const float4* p = (const float4*)(W + (size_t)(n0 + row) * K + k0 + col);
                float4 u0 = p[0], u1 = p[1];
                bf16x8 v;
                v[0] = (bf16)u0.x; v[1] = (bf16)u0.y; v[2] = (bf16)u0.z; v[3] = (bf16)u0.w;
                v[4] = (bf16)u1.x; v[5] = (bf16)u1.y; v[6] = (bf16)u1.z; v[7] = (bf16)u1.w;
                *(bf16x8*)(&Ws[row * 64 + col]) = v;
            }
        } else {
            const bf16* W = (const bf16*)Wp;
            #pragma unroll
            for (int ch = 0; ch < 4; ch++) {
                int row = wv * 32 + ch * 8 + arow;
                async16(W + (size_t)(n0 + row) * K + k0 + acol,
                        &Ws[(wv * 32 + ch * 8) * 64]);
            }
        }
        __syncthreads();

        #pragma unroll
        for (int t = 0; t < 2; t++) {
            bf16x8 af[4], bw[4];
            #pragma unroll
            for (int i = 0; i < 4; i++)
                af[i] = *(const bf16x8*)(&As[(wm + i * 16 + c) * 64 + t * 32 + quad * 8]);
            #pragma unroll
            for (int j = 0; j < 4; j++)
                bw[j] = *(const bf16x8*)(&Ws[(wn + j * 16 + c) * 64 + t * 32 + quad * 8]);
            #pragma unroll
            for (int i = 0; i < 4; i++)
                #pragma unroll
                for (int j = 0; j < 4; j++)
                    acc[i][j] = __builtin_amdgcn_mfma_f32_16x16x32_bf16(af[i], bw[j], acc[i][j], 0, 0, 0);
        }
        __syncthreads();
    }

    if constexpr (CMODE == 0) {
        float* C = (float*)Cp;
        #pragma unroll
        for (int i = 0; i < 4; i++)
            #pragma unroll
            for (int j = 0; j < 4; j++)
                #pragma unroll
                for (int r = 0; r < 4; r++) {
                    int m = m0 + wm + i * 16 + quad * 4 + r;
                    int n = n0 + wn + j * 16 + c;
                    C[(size_t)m * N + n] = acc[i][j][r];
                }
    } else if constexpr (CMODE == 1) {
        bf16* C = (bf16*)Cp;
        #pragma unroll
        for (int i = 0; i < 4; i++)
            #pragma unroll
            for (int j = 0; j < 4; j++)
                #pragma unroll
                for (int r = 0; r < 4; r++) {
                    int m = m0 + wm + i * 16 + quad * 4 + r;
                    int n = n0 + wn + j * 16 + c;
                    C[(size_t)m * N + n] = (bf16)acc[i][j][r];
                }
    } else if constexpr (CMODE == 2) {
        bf16* C = (bf16*)Cp;
        const int b = m0 >> 11;
        #pragma unroll
        for (int j = 0; j < 4; j++) {
            int n = n0 + wn + j * 16 + c;
            size_t base = ((size_t)b * N + n) * 2048;
            #pragma unroll
            for (int i = 0; i < 4; i++) {
                int s0 = (m0 & 2047) + wm + i * 16 + quad * 4;
                bf16x4 v;
                #pragma unroll
                for (int r = 0; r < 4; r++) v[r] = (bf16)acc[i][j][r];
                *(bf16x4*)(&C[base + s0]) = v;
            }
        }
    } else {
        bf16* Cq = (bf16*)Cp;
        if (n0 < 2048) {
            #pragma unroll
            for (int i = 0; i < 4; i++)
                #pragma unroll
                for (int j = 0; j < 4; j++)
                    #pragma unroll
                    for (int r = 0; r < 4; r++) {
                        int m = m0 + wm + i * 16 + quad * 4 + r;
                        int n = n0 + wn + j * 16 + c;
                        Cq[(size_t)m * 2048 + n] = (bf16)acc[i][j][r];
                    }
        } else if (n0 < 3072) {
            bf16* Ck = Cq + XN;
            #pragma unroll
            for (int i = 0; i < 4; i++)
                #pragma unroll
                for (int j = 0; j < 4; j++)
                    #pragma unroll
                    for (int r = 0; r < 4; r++) {
                        int m = m0 + wm + i * 16 + quad * 4 + r;
                        int n = n0 - 2048 + wn + j * 16 + c;
                        Ck[(size_t)m * 1024 + n] = (bf16)acc[i][j][r];
                    }
        } else {
            bf16* Cv = Cq + XN + QWN;
            const int b = m0 >> 11;
            #pragma unroll
            for (int j = 0; j < 4; j++) {
                int n = n0 - 3072 + wn + j * 16 + c;
                size_t base = ((size_t)b * 1024 + n) * 2048;
                #pragma unroll
                for (int i = 0; i < 4; i++) {
                    int s0 = (m0 & 2047) + wm + i * 16 + quad * 4;
                    bf16x4 v;
                    #pragma unroll
                    for (int r = 0; r < 4; r++) v[r] = (bf16)acc[i][j][r];
                    *(bf16x4*)(&Cv[base + s0]) = v;
                }
            }
        }
    }
}

// ---------------------------------------------------------------------------
// RMSNorm(D=128) + RoPE for K ONLY.
// ---------------------------------------------------------------------------
__global__ __launch_bounds__(128) void norm_rope_k(bf16* __restrict__ k,
                                                   const float* __restrict__ pe,
                                                   const float* __restrict__ knw)
{
    const int s  = blockIdx.x;
    const int hh = blockIdx.y;
    const int b  = blockIdx.z;
    const int d  = threadIdx.x;

    bf16* buf = k + (size_t)(b * SEQ + s) * 1024 + hh * HD;

    float x = (float)buf[d];
    float ss = x * x;
    #pragma unroll
    for (int m = 32; m; m >>= 1) ss += __shfl_xor(ss, m);

    __shared__ float red[2];
    __shared__ float nv[128];
    if ((d & 63) == 0) red[d >> 6] = ss;
    __syncthreads();
    float var = (red[0] + red[1]) * (1.0f / 128.0f);
    float nx = x * rsqrtf(var + 1e-6f) * knw[d];
    nv[d] = nx;
    __syncthreads();

    const float* pev = pe + ((size_t)b * SEQ + s) * HD;
    float o;
    if (d < 64) {
        o = nx * pev[d] - nv[d + 64] * pev[64 + d];
    } else {
        o = nv[d - 64] * pev[d] + nx * pev[d - 64];
    }
    buf[d] = (bf16)o;
}

// ---------------------------------------------------------------------------
// Flash attention, causal, GQA rep=2.  8 waves x 16 q-rows = 128 q rows per
// block; grid (SEQ/128, BATCH, NH): CU hosts blocks i and i+256 which differ
// by h->h+8, so the (h&8) qblk flip pairs complementary causal workloads.
// ---------------------------------------------------------------------------
__global__ __launch_bounds__(512) void fattn(bf16* __restrict__ O,
                                             const bf16* __restrict__ Q,
                                             const bf16* __restrict__ Kh,
                                             const bf16* __restrict__ Vtg,
                                             const float* __restrict__ pe,
                                             const float* __restrict__ qnw)
{
    const int h    = blockIdx.z;
    const int b    = blockIdx.y;
    const int qblk = (h & 8) ? (int)blockIdx.x
                             : ((int)gridDim.x - 1 - (int)blockIdx.x);
    const int kv   = h >> 1;

    const int tid  = threadIdx.x;
    const int wv   = tid >> 6;           // 0..7
    const int lane = tid & 63;
    const int quad = lane >> 4;
    const int c    = lane & 15;

    __shared__ bf16 Ks[64 * 136];        // [key][d]
    __shared__ bf16 Vs[128 * 72];        // [d][key]
    __shared__ bf16 Ps[8 * 16 * 72];     // per-wave P tile

    const int qw = qblk * 128 + wv * 16;

    // ---- prologue: load raw q row, RMSNorm + RoPE in registers ----
    bf16x8 qf[4];
    {
        const bf16* qp = Q + (size_t)(b * SEQ + qw + c) * 2048 + h * HD + quad * 8;
        float qv[4][8];
        float ss = 0.0f;
        #pragma unroll
        for (int t = 0; t < 4; t++) {
            bf16x8 raw = *(const bf16x8*)(qp + t * 32);
            #pragma unroll
            for (int j = 0; j < 8; j++) { qv[t][j] = (float)raw[j]; ss += qv[t][j] * qv[t][j]; }
        }
        ss += __shfl_xor(ss, 16);
        ss += __shfl_xor(ss, 32);
        const float inv = rsqrtf(ss * (1.0f / 128.0f) + 1e-6f);
        const float* pev = pe + (size_t)(b * SEQ + qw + c) * HD + quad * 8;
        float nx[4][8], pv[4][8];
        #pragma unroll
        for (int t = 0; t < 4; t++)
            #pragma unroll
            for (int j = 0; j < 8; j++) {
                pv[t][j] = pev[t * 32 + j];
                nx[t][j] = qv[t][j] * inv * qnw[t * 32 + quad * 8 + j];
            }
        #pragma unroll
        for (int t = 0; t < 2; t++)
            #pragma unroll
            for (int j = 0; j < 8; j++) {
                qf[t][j]     = (bf16)(nx[t][j] * pv[t][j]     - nx[t + 2][j] * pv[t + 2][j]);
                qf[t + 2][j] = (bf16)(nx[t][j] * pv[t + 2][j] + nx[t + 2][j] * pv[t][j]);
            }
    }

    floatx4 o_acc[8] = {};
    float l_part[4] = {};

    const bf16* kbase = Kh  + (size_t)b * SEQ * 1024 + kv * HD;        // + s*1024
    const bf16* vbase = Vtg + ((size_t)b * 1024 + kv * HD) * 2048;     // + d*2048

    const int kr  = tid >> 3, ksc = (tid & 7) * 16;   // K staging: 64 rows x 128
    const int vd  = tid >> 2, vkc = (tid & 3) * 16;   // V^T staging: 128 rows x 64
    bf16* psw = &Ps[wv * 16 * 72];
    const int nkt = 2 * qblk + 2;
    const float kS = 0.08838834764831845f * 1.4426950408889634f;  // scale*log2e
    const float kB = 11.5f * 1.4426950408889634f;                 // M*log2e

    // ---- load tile 0 into registers ----
    bf16x8 kreg[2], vreg[2];
    {
        const bf16* kp = kbase + (size_t)kr * 1024 + ksc;
        const bf16* vp = vbase + (size_t)vd * 2048 + vkc;
        kreg[0] = *(const bf16x8*)(kp);
        kreg[1] = *(const bf16x8*)(kp + 8);
        vreg[0] = *(const bf16x8*)(vp);
        vreg[1] = *(const bf16x8*)(vp + 8);
    }

    for (int kt = 0; kt < nkt; kt++) {
        const int k0 = kt * 64;
        *(bf16x8*)(&Ks[kr * 136 + ksc])     = kreg[0];
        *(bf16x8*)(&Ks[kr * 136 + ksc + 8]) = kreg[1];
        *(bf16x8*)(&Vs[vd * 72 + vkc])      = vreg[0];
        *(bf16x8*)(&Vs[vd * 72 + vkc + 8])  = vreg[1];
        __syncthreads();

        if (kt + 1 < nkt) {
            const bf16* kp = kbase + (size_t)(k0 + 64 + kr) * 1024 + ksc;
            const bf16* vp = vbase + (size_t)vd * 2048 + (k0 + 64) + vkc;
            kreg[0] = *(const bf16x8*)(kp);
            kreg[1] = *(const bf16x8*)(kp + 8);
            vreg[0] = *(const bf16x8*)(vp);
            vreg[1] = *(const bf16x8*)(vp + 8);
        }

        if (k0 <= qw + 15) {
            floatx4 sc[4] = {};
            #pragma unroll
            for (int t = 0; t < 4; t++) {
                #pragma unroll
                for (int g = 0; g < 4; g++) {
                    bf16x8 kf = *(const bf16x8*)(&Ks[(g * 16 + c) * 136 + t * 32 + quad * 8]);
                    sc[g] = __builtin_amdgcn_mfma_f32_16x16x32_bf16(qf[t], kf, sc[g], 0, 0, 0);
                }
            }

            const bool tail = (kt >= nkt - 2);
            #pragma unroll
            for (int r = 0; r < 4; r++) {
                const int qrow = qw + quad * 4 + r;
                #pragma unroll
                for (int g = 0; g < 4; g++) {
                    float p = exp2f(sc[g][r] * kS - kB);
                    if (tail && (k0 + g * 16 + c > qrow)) p = 0.0f;
                    l_part[r] += p;
                    psw[(quad * 4 + r) * 72 + g * 16 + c] = (bf16)p;
                }
            }
            asm volatile("s_waitcnt lgkmcnt(0)" ::: "memory");
            bf16x8 pf0 = *(const bf16x8*)(&psw[c * 72 + quad * 8]);
            bf16x8 pf1 = *(const bf16x8*)(&psw[c * 72 + 32 + quad * 8]);

            #pragma unroll
            for (int f = 0; f < 8; f++) {
                bf16x8 vf0 = *(const bf16x8*)(&Vs[(f * 16 + c) * 72 + quad * 8]);
                bf16x8 vf1 = *(const bf16x8*)(&Vs[(f * 16 + c) * 72 + 32 + quad * 8]);
                o_acc[f] = __builtin_amdgcn_mfma_f32_16x16x32_bf16(pf0, vf0, o_acc[f], 0, 0, 0);
                o_acc[f] = __builtin_amdgcn_mfma_f32_16x16x32_bf16(pf1, vf1, o_acc[f], 0, 0, 0);
            }
        }
        __syncthreads();
    }

    #pragma unroll
    for (int r = 0; r < 4; r++) {
        float l = l_part[r];
        #pragma unroll
        for (int msk = 8; msk; msk >>= 1) l += __shfl_xor(l, msk);
        const float inv = 1.0f / l;
        bf16* op = O + (size_t)(b * SEQ + qw + quad * 4 + r) * 2048 + h * HD;
        #pragma unroll
        for (int f = 0; f < 8; f++) op[f * 16 + c] = (bf16)(o_acc[f][r] * inv);
    }
}

// ---------------------------------------------------------------------------
extern "C" void kernel_launch(void* const* d_in, const int* in_sizes, int n_in,
                              void* d_out, int out_size, void* d_ws, size_t ws_size,
                              hipStream_t stream)
{
    const float* x   = (const float*)d_in[0];
    const float* pe  = (const float*)d_in[1];
    const float* qw  = (const float*)d_in[2];
    const float* kw  = (const float*)d_in[3];
    const float* vw  = (const float*)d_in[4];
    const float* ow  = (const float*)d_in[5];
    const float* qnw = (const float*)d_in[6];
    const float* knw = (const float*)d_in[7];
    float* out = (float*)d_out;

    bf16* qb = (bf16*)d_ws;          // [B][S][2048]   row-major (raw q)
    bf16* kb = qb + XN;              // [B][S][1024]   row-major
    bf16* vt = kb + KWN * 2;         // [B][1024][2048] V^T
    bf16* ab = vt + VWN * 2;         // [B][S][2048]   row-major
    bf16* cvt_base = ab + XN;

    const bool fit = ws_size >= (size_t)92274688;
    const int M = BATCH * SEQ;

    if (fit) {
        bf16* xb  = cvt_base;
        bf16* qwb = xb  + XN;
        bf16* owb = qwb + QWN + KWN + VWN;

        cvt_all<<<10240, 256, 0, stream>>>(xb, x, qw, kw, vw, ow);

        gemm256_qkv<<<dim3(16, 16), 512, 0, stream>>>(qb, xb, qwb);

        norm_rope_k<<<dim3(SEQ, NKV, BATCH), 128, 0, stream>>>(kb, pe, knw);
        fattn<<<dim3(SEQ / 128, BATCH, NH), 512, 0, stream>>>(ab, qb, kb, vt, pe, qnw);

        gemm128<1, 1, 0><<<dim3(32, 16), 256, 0, stream>>>(out, ab, owb, M, 2048, 2048);
    } else {
        gemm128<0, 0, 1><<<dim3(32, 16), 256, 0, stream>>>(qb, x, qw, M, 2048, 2048);
        gemm128<0, 0, 1><<<dim3(32,  8), 256, 0, stream>>>(kb, x, kw, M, 1024, 2048);
        gemm128<0, 0, 2><<<dim3(32,  8), 256, 0, stream>>>(vt, x, vw, M, 1024, 2048);

        norm_rope_k<<<dim3(SEQ, NKV, BATCH), 128, 0, stream>>>(kb, pe, knw);
        fattn<<<dim3(SEQ / 128, BATCH, NH), 512, 0, stream>>>(ab, qb, kb, vt, pe, qnw);

        gemm128<0, 0, 0><<<dim3(32, 16), 256, 0, stream>>>(out, ab, ow, M, 2048, 2048);
    }
}

// Round 10
// 335.330 us; speedup vs baseline: 1.3133x; 1.0716x over previous
//
#include <hip/hip_runtime.h>
#include <hip/hip_bf16.h>

#define BATCH 2
#define SEQ   2048
#define HID   2048
#define NH    16
#define NKV   8
#define HD    128

typedef __bf16 bf16;
typedef bf16  bf16x8  __attribute__((ext_vector_type(8)));
typedef bf16  bf16x4  __attribute__((ext_vector_type(4)));
typedef float floatx4 __attribute__((ext_vector_type(4)));

typedef __attribute__((address_space(3))) void lds_void;
typedef const __attribute__((address_space(1))) void gmem_void;

__device__ inline void async16(const void* g, void* l) {
    __builtin_amdgcn_global_load_lds((gmem_void*)g, (lds_void*)l, 16, 0, 0);
}

// workspace layout constants (elements)
#define XN  8388608u
#define QWN 4194304u
#define KWN 2097152u
#define VWN 2097152u
#define OWN 4194304u

// ---------------------------------------------------------------------------
// Fused f32 -> bf16 convert for x + all four weights in ONE launch.
// ---------------------------------------------------------------------------
__global__ __launch_bounds__(256) void cvt_all(bf16* __restrict__ dst,
                                               const float* __restrict__ x,
                                               const float* __restrict__ qw,
                                               const float* __restrict__ kw,
                                               const float* __restrict__ vw,
                                               const float* __restrict__ ow)
{
    const int blk = blockIdx.x;
    const float* src;
    size_t off;
    if (blk < 4096)      { src = x;  off = (size_t)blk * 2048; }
    else if (blk < 6144) { src = qw; off = (size_t)(blk - 4096) * 2048; }
    else if (blk < 7168) { src = kw; off = (size_t)(blk - 6144) * 2048; }
    else if (blk < 8192) { src = vw; off = (size_t)(blk - 7168) * 2048; }
    else                 { src = ow; off = (size_t)(blk - 8192) * 2048; }

    const int t = threadIdx.x * 8;
    const float4* p = (const float4*)(src + off + t);
    float4 u0 = p[0], u1 = p[1];
    bf16x8 v;
    v[0] = (bf16)u0.x; v[1] = (bf16)u0.y; v[2] = (bf16)u0.z; v[3] = (bf16)u0.w;
    v[4] = (bf16)u1.x; v[5] = (bf16)u1.y; v[6] = (bf16)u1.z; v[7] = (bf16)u1.w;
    *(bf16x8*)(dst + (size_t)blk * 2048 + t) = v;
}

// ---------------------------------------------------------------------------
// Fused QKV projection GEMM, 256x256 tile, BK=64, 8 waves, double-buffered
// LDS (128 KB), ONE barrier per K-tile.  T2 XOR-swizzle: LDS[row][chunk] =
// global[row][chunk ^ (row&7)] (pre-swizzled global source, linear LDS
// dest -- global_load_lds constraint); reads XOR the same field.  Kills the
// 16-way stride-128B ds_read conflict (1.9e7 -> ~0).
// ---------------------------------------------------------------------------
__global__ __launch_bounds__(512) void gemm256_qkv(bf16* __restrict__ Cq,
                                                   const bf16* __restrict__ A,
                                                   const bf16* __restrict__ W)
{
    __shared__ bf16 As[2 * 256 * 64];   // 64 KB
    __shared__ bf16 Ws[2 * 256 * 64];   // 64 KB

    const int tid  = threadIdx.x;
    const int wv   = tid >> 6;           // 0..7
    const int lane = tid & 63;
    const int quad = lane >> 4;
    const int c    = lane & 15;

    // XCD-aware bijective swizzle over 256 blocks.
    int lin = blockIdx.y * gridDim.x + blockIdx.x;
    lin = (lin & 7) * 32 + (lin >> 3);
    const int m0 = (lin & 15) * 256;
    const int n0 = (lin >> 4) * 256;

    const int wm = (wv >> 2) * 128;      // 0 / 128
    const int wn = (wv & 3) * 64;        // 0 / 64 / 128 / 192

    const int srow = tid >> 3;                                  // 0..63
    const int scol = (((tid & 7) ^ ((tid >> 3) & 7))) * 8;      // swizzled source chunk
    const int rsw  = (c & 7) * 8;                               // read-side XOR field

    constexpr int K  = 2048;
    constexpr int NT = K / 64;

    floatx4 acc[8][4] = {};

    auto stage = [&](int kt, int sel) {
        const size_t ko = (size_t)kt * 64;
        bf16* Ab = &As[sel * 16384];
        bf16* Wb = &Ws[sel * 16384];
        #pragma unroll
        for (int l = 0; l < 4; ++l)
            async16(A + (size_t)(m0 + l * 64 + srow) * K + ko + scol,
                    Ab + l * 4096 + wv * 512);
        #pragma unroll
        for (int l = 0; l < 4; ++l)
            async16(W + (size_t)(n0 + l * 64 + srow) * K + ko + scol,
                    Wb + l * 4096 + wv * 512);
    };

    stage(0, 0);

    int sel = 0;
    for (int t = 0; t < NT; ++t) {
        __syncthreads();                 // drain vmcnt (tile t landed, all waves)
        if (t + 1 < NT) stage(t + 1, sel ^ 1);

        const bf16* Ab = &As[sel * 16384];
        const bf16* Wb = &Ws[sel * 16384];
        #pragma unroll
        for (int ks = 0; ks < 2; ++ks) {
            const int ro = (ks * 32 + quad * 8) ^ rsw;   // swizzled read offset
            bf16x8 af[8], bw[4];
            #pragma unroll
            for (int i = 0; i < 8; i++)
                af[i] = *(const bf16x8*)(Ab + (wm + i * 16 + c) * 64 + ro);
            #pragma unroll
            for (int j = 0; j < 4; j++)
                bw[j] = *(const bf16x8*)(Wb + (wn + j * 16 + c) * 64 + ro);
            __builtin_amdgcn_s_setprio(1);
            #pragma unroll
            for (int i = 0; i < 8; i++)
                #pragma unroll
                for (int j = 0; j < 4; j++)
                    acc[i][j] = __builtin_amdgcn_mfma_f32_16x16x32_bf16(af[i], bw[j], acc[i][j], 0, 0, 0);
            __builtin_amdgcn_s_setprio(0);
        }
        sel ^= 1;
    }

    // ---- epilogue: fused QKV split (q | k | v^T) ----
    const int b = m0 >> 11;
    if (n0 < 2048) {
        #pragma unroll
        for (int i = 0; i < 8; i++)
            #pragma unroll
            for (int j = 0; j < 4; j++)
                #pragma unroll
                for (int r = 0; r < 4; r++) {
                    int m = m0 + wm + i * 16 + quad * 4 + r;
                    int n = n0 + wn + j * 16 + c;
                    Cq[(size_t)m * 2048 + n] = (bf16)acc[i][j][r];
                }
    } else if (n0 < 3072) {
        bf16* Ck = Cq + XN;
        #pragma unroll
        for (int i = 0; i < 8; i++)
            #pragma unroll
            for (int j = 0; j < 4; j++)
                #pragma unroll
                for (int r = 0; r < 4; r++) {
                    int m = m0 + wm + i * 16 + quad * 4 + r;
                    int n = n0 - 2048 + wn + j * 16 + c;
                    Ck[(size_t)m * 1024 + n] = (bf16)acc[i][j][r];
                }
    } else {
        bf16* Cv = Cq + XN + QWN;
        #pragma unroll
        for (int j = 0; j < 4; j++) {
            int n = n0 - 3072 + wn + j * 16 + c;
            size_t base = ((size_t)b * 1024 + n) * 2048;
            #pragma unroll
            for (int i = 0; i < 8; i++) {
                int s0 = (m0 & 2047) + wm + i * 16 + quad * 4;
                bf16x4 v;
                #pragma unroll
                for (int r = 0; r < 4; r++) v[r] = (bf16)acc[i][j][r];
                *(bf16x4*)(&Cv[base + s0]) = v;
            }
        }
    }
}

// ---------------------------------------------------------------------------
// GEMM  C = A[M,K] * W[N,K]^T, 128x128 tile, BK=64.  (fallback + O-proj)
// Same T2 XOR-swizzle as gemm256_qkv (both write paths + reads).
// ---------------------------------------------------------------------------
template <int AMODE, int WMODE, int CMODE>
__global__ __launch_bounds__(256) void gemm128(void* __restrict__ Cp,
                                               const void* __restrict__ Ap,
                                               const void* __restrict__ Wp,
                                               int M, int N, int K)
{
    __shared__ bf16 As[128 * 64];
    __shared__ bf16 Ws[128 * 64];

    const int tid  = threadIdx.x;
    const int wv   = tid >> 6;
    const int lane = tid & 63;
    const int quad = lane >> 4;
    const int c    = lane & 15;

    const int nwg = gridDim.x * gridDim.y;
    int bx = blockIdx.x, by = blockIdx.y;
    if ((nwg & 7) == 0) {
        int lin = by * gridDim.x + bx;
        lin = (lin & 7) * (nwg >> 3) + (lin >> 3);
        bx = lin % gridDim.x;
        by = lin / gridDim.x;
    }
    const int m0 = bx * 128;
    const int n0 = by * 128;
    const int wm = (wv >> 1) * 64;
    const int wn = (wv & 1) * 64;

    const int arow   = lane >> 3;
    const int acolsw = (((lane & 7) ^ (lane >> 3))) * 8;   // swizzled source chunk
    const int wsw    = ((tid >> 3) & 7) * 8;               // AMODE0 write XOR field
    const int rsw    = (c & 7) * 8;                        // read XOR field

    floatx4 acc[4][4] = {};

    for (int k0 = 0; k0 < K; k0 += 64) {
        if constexpr (AMODE == 0) {
            const float* A = (const float*)Ap;
            #pragma unroll
            for (int it = 0; it < 4; it++) {
                int row = it * 32 + (tid >> 3);
                int col = (tid & 7) * 8;
                const float4* p = (const float4*)(A + (size_t)(m0 + row) * K + k0 + col);
                float4 u0 = p[0], u1 = p[1];
                bf16x8 v;
                v[0] = (bf16)u0.x; v[1] = (bf16)u0.y; v[2] = (bf16)u0.z; v[3] = (bf16)u0.w;
                v[4] = (bf16)u1.x; v[5] = (bf16)u1.y; v[6] = (bf16)u1.z; v[7] = (bf16)u1.w;
                *(bf16x8*)(&As[row * 64 + (col ^ wsw)]) = v;
            }
        } else {
            const bf16* A = (const bf16*)Ap;
            #pragma unroll
            for (int ch = 0; ch < 4; ch++) {
                int row = wv * 32 + ch * 8 + arow;
                async16(A + (size_t)(m0 + row) * K + k0 + acolsw,
                        &As[(wv * 32 + ch * 8) * 64]);
            }
        }
        if constexpr (WMODE == 0) {
            const float* W = (const float*)Wp;
            #pragma unroll
            for (int it = 0; it < 4; it++) {
                int row = it * 32 + (tid >> 3);
                int col = (tid & 7) * 8;
                const float4* p = (const float4*)(W + (size_t)(n0 + row) * K + k0 + col);
                float4 u0 = p[0], u1 = p[1];
                bf16x8 v;
                v[0] = (bf16)u0.x; v[1] = (bf16)u0.y; v[2] = (bf16)u0.z; v[3] = (bf16)u0.w;
                v[4] = (bf16)u1.x; v[5] = (bf16)u1.y; v[6] = (bf16)u1.z; v[7] = (bf16)u1.w;
                *(bf16x8*)(&Ws[row * 64 + (col ^ wsw)]) = v;
            }
        } else {
            const bf16* W = (const bf16*)Wp;
            #pragma unroll
            for (int ch = 0; ch < 4; ch++) {
                int row = wv * 32 + ch * 8 + arow;
                async16(W + (size_t)(n0 + row) * K + k0 + acolsw,
                        &Ws[(wv * 32 + ch * 8) * 64]);
            }
        }
        __syncthreads();

        #pragma unroll
        for (int t = 0; t < 2; t++) {
            const int ro = (t * 32 + quad * 8) ^ rsw;
            bf16x8 af[4], bw[4];
            #pragma unroll
            for (int i = 0; i < 4; i++)
                af[i] = *(const bf16x8*)(&As[(wm + i * 16 + c) * 64 + ro]);
            #pragma unroll
            for (int j = 0; j < 4; j++)
                bw[j] = *(const bf16x8*)(&Ws[(wn + j * 16 + c) * 64 + ro]);
            #pragma unroll
            for (int i = 0; i < 4; i++)
                #pragma unroll
                for (int j = 0; j < 4; j++)
                    acc[i][j] = __builtin_amdgcn_mfma_f32_16x16x32_bf16(af[i], bw[j], acc[i][j], 0, 0, 0);
        }
        __syncthreads();
    }

    if constexpr (CMODE == 0) {
        float* C = (float*)Cp;
        #pragma unroll
        for (int i = 0; i < 4; i++)
            #pragma unroll
            for (int j = 0; j < 4; j++)
                #pragma unroll
                for (int r = 0; r < 4; r++) {
                    int m = m0 + wm + i * 16 + quad * 4 + r;
                    int n = n0 + wn + j * 16 + c;
                    C[(size_t)m * N + n] = acc[i][j][r];
                }
    } else if constexpr (CMODE == 1) {
        bf16* C = (bf16*)Cp;
        #pragma unroll
        for (int i = 0; i < 4; i++)
            #pragma unroll
            for (int j = 0; j < 4; j++)
                #pragma unroll
                for (int r = 0; r < 4; r++) {
                    int m = m0 + wm + i * 16 + quad * 4 + r;
                    int n = n0 + wn + j * 16 + c;
                    C[(size_t)m * N + n] = (bf16)acc[i][j][r];
                }
    } else if constexpr (CMODE == 2) {
        bf16* C = (bf16*)Cp;
        const int b = m0 >> 11;
        #pragma unroll
        for (int j = 0; j < 4; j++) {
            int n = n0 + wn + j * 16 + c;
            size_t base = ((size_t)b * N + n) * 2048;
            #pragma unroll
            for (int i = 0; i < 4; i++) {
                int s0 = (m0 & 2047) + wm + i * 16 + quad * 4;
                bf16x4 v;
                #pragma unroll
                for (int r = 0; r < 4; r++) v[r] = (bf16)acc[i][j][r];
                *(bf16x4*)(&C[base + s0]) = v;
            }
        }
    } else {
        bf16* Cq = (bf16*)Cp;
        if (n0 < 2048) {
            #pragma unroll
            for (int i = 0; i < 4; i++)
                #pragma unroll
                for (int j = 0; j < 4; j++)
                    #pragma unroll
                    for (int r = 0; r < 4; r++) {
                        int m = m0 + wm + i * 16 + quad * 4 + r;
                        int n = n0 + wn + j * 16 + c;
                        Cq[(size_t)m * 2048 + n] = (bf16)acc[i][j][r];
                    }
        } else if (n0 < 3072) {
            bf16* Ck = Cq + XN;
            #pragma unroll
            for (int i = 0; i < 4; i++)
                #pragma unroll
                for (int j = 0; j < 4; j++)
                    #pragma unroll
                    for (int r = 0; r < 4; r++) {
                        int m = m0 + wm + i * 16 + quad * 4 + r;
                        int n = n0 - 2048 + wn + j * 16 + c;
                        Ck[(size_t)m * 1024 + n] = (bf16)acc[i][j][r];
                    }
        } else {
            bf16* Cv = Cq + XN + QWN;
            const int b = m0 >> 11;
            #pragma unroll
            for (int j = 0; j < 4; j++) {
                int n = n0 - 3072 + wn + j * 16 + c;
                size_t base = ((size_t)b * 1024 + n) * 2048;
                #pragma unroll
                for (int i = 0; i < 4; i++) {
                    int s0 = (m0 & 2047) + wm + i * 16 + quad * 4;
                    bf16x4 v;
                    #pragma unroll
                    for (int r = 0; r < 4; r++) v[r] = (bf16)acc[i][j][r];
                    *(bf16x4*)(&Cv[base + s0]) = v;
                }
            }
        }
    }
}

// ---------------------------------------------------------------------------
// RMSNorm(D=128) + RoPE for K ONLY.
// ---------------------------------------------------------------------------
__global__ __launch_bounds__(128) void norm_rope_k(bf16* __restrict__ k,
                                                   const float* __restrict__ pe,
                                                   const float* __restrict__ knw)
{
    const int s  = blockIdx.x;
    const int hh = blockIdx.y;
    const int b  = blockIdx.z;
    const int d  = threadIdx.x;

    bf16* buf = k + (size_t)(b * SEQ + s) * 1024 + hh * HD;

    float x = (float)buf[d];
    float ss = x * x;
    #pragma unroll
    for (int m = 32; m; m >>= 1) ss += __shfl_xor(ss, m);

    __shared__ float red[2];
    __shared__ float nv[128];
    if ((d & 63) == 0) red[d >> 6] = ss;
    __syncthreads();
    float var = (red[0] + red[1]) * (1.0f / 128.0f);
    float nx = x * rsqrtf(var + 1e-6f) * knw[d];
    nv[d] = nx;
    __syncthreads();

    const float* pev = pe + ((size_t)b * SEQ + s) * HD;
    float o;
    if (d < 64) {
        o = nx * pev[d] - nv[d + 64] * pev[64 + d];
    } else {
        o = nv[d - 64] * pev[d] + nx * pev[d - 64];
    }
    buf[d] = (bf16)o;
}

// ---------------------------------------------------------------------------
// Flash attention, causal, GQA rep=2.  8 waves x 16 q-rows = 128 q rows per
// block; grid (SEQ/128, BATCH, NH): CU hosts blocks i and i+256 which differ
// by h->h+8, so the (h&8) qblk flip pairs complementary causal workloads.
// ---------------------------------------------------------------------------
__global__ __launch_bounds__(512) void fattn(bf16* __restrict__ O,
                                             const bf16* __restrict__ Q,
                                             const bf16* __restrict__ Kh,
                                             const bf16* __restrict__ Vtg,
                                             const float* __restrict__ pe,
                                             const float* __restrict__ qnw)
{
    const int h    = blockIdx.z;
    const int b    = blockIdx.y;
    const int qblk = (h & 8) ? (int)blockIdx.x
                             : ((int)gridDim.x - 1 - (int)blockIdx.x);
    const int kv   = h >> 1;

    const int tid  = threadIdx.x;
    const int wv   = tid >> 6;           // 0..7
    const int lane = tid & 63;
    const int quad = lane >> 4;
    const int c    = lane & 15;

    __shared__ bf16 Ks[64 * 136];        // [key][d]
    __shared__ bf16 Vs[128 * 72];        // [d][key]
    __shared__ bf16 Ps[8 * 16 * 72];     // per-wave P tile

    const int qw = qblk * 128 + wv * 16;

    // ---- prologue: load raw q row, RMSNorm + RoPE in registers ----
    bf16x8 qf[4];
    {
        const bf16* qp = Q + (size_t)(b * SEQ + qw + c) * 2048 + h * HD + quad * 8;
        float qv[4][8];
        float ss = 0.0f;
        #pragma unroll
        for (int t = 0; t < 4; t++) {
            bf16x8 raw = *(const bf16x8*)(qp + t * 32);
            #pragma unroll
            for (int j = 0; j < 8; j++) { qv[t][j] = (float)raw[j]; ss += qv[t][j] * qv[t][j]; }
        }
        ss += __shfl_xor(ss, 16);
        ss += __shfl_xor(ss, 32);
        const float inv = rsqrtf(ss * (1.0f / 128.0f) + 1e-6f);
        const float* pev = pe + (size_t)(b * SEQ + qw + c) * HD + quad * 8;
        float nx[4][8], pv[4][8];
        #pragma unroll
        for (int t = 0; t < 4; t++)
            #pragma unroll
            for (int j = 0; j < 8; j++) {
                pv[t][j] = pev[t * 32 + j];
                nx[t][j] = qv[t][j] * inv * qnw[t * 32 + quad * 8 + j];
            }
        #pragma unroll
        for (int t = 0; t < 2; t++)
            #pragma unroll
            for (int j = 0; j < 8; j++) {
                qf[t][j]     = (bf16)(nx[t][j] * pv[t][j]     - nx[t + 2][j] * pv[t + 2][j]);
                qf[t + 2][j] = (bf16)(nx[t][j] * pv[t + 2][j] + nx[t + 2][j] * pv[t][j]);
            }
    }

    floatx4 o_acc[8] = {};
    float l_part[4] = {};

    const bf16* kbase = Kh  + (size_t)b * SEQ * 1024 + kv * HD;        // + s*1024
    const bf16* vbase = Vtg + ((size_t)b * 1024 + kv * HD) * 2048;     // + d*2048

    const int kr  = tid >> 3, ksc = (tid & 7) * 16;   // K staging: 64 rows x 128
    const int vd  = tid >> 2, vkc = (tid & 3) * 16;   // V^T staging: 128 rows x 64
    bf16* psw = &Ps[wv * 16 * 72];
    const int nkt = 2 * qblk + 2;
    const float kS = 0.08838834764831845f * 1.4426950408889634f;  // scale*log2e
    const float kB = 11.5f * 1.4426950408889634f;                 // M*log2e

    // ---- load tile 0 into registers ----
    bf16x8 kreg[2], vreg[2];
    {
        const bf16* kp = kbase + (size_t)kr * 1024 + ksc;
        const bf16* vp = vbase + (size_t)vd * 2048 + vkc;
        kreg[0] = *(const bf16x8*)(kp);
        kreg[1] = *(const bf16x8*)(kp + 8);
        vreg[0] = *(const bf16x8*)(vp);
        vreg[1] = *(const bf16x8*)(vp + 8);
    }

    for (int kt = 0; kt < nkt; kt++) {
        const int k0 = kt * 64;
        *(bf16x8*)(&Ks[kr * 136 + ksc])     = kreg[0];
        *(bf16x8*)(&Ks[kr * 136 + ksc + 8]) = kreg[1];
        *(bf16x8*)(&Vs[vd * 72 + vkc])      = vreg[0];
        *(bf16x8*)(&Vs[vd * 72 + vkc + 8])  = vreg[1];
        __syncthreads();

        if (kt + 1 < nkt) {
            const bf16* kp = kbase + (size_t)(k0 + 64 + kr) * 1024 + ksc;
            const bf16* vp = vbase + (size_t)vd * 2048 + (k0 + 64) + vkc;
            kreg[0] = *(const bf16x8*)(kp);
            kreg[1] = *(const bf16x8*)(kp + 8);
            vreg[0] = *(const bf16x8*)(vp);
            vreg[1] = *(const bf16x8*)(vp + 8);
        }

        if (k0 <= qw + 15) {
            floatx4 sc[4] = {};
            #pragma unroll
            for (int t = 0; t < 4; t++) {
                #pragma unroll
                for (int g = 0; g < 4; g++) {
                    bf16x8 kf = *(const bf16x8*)(&Ks[(g * 16 + c) * 136 + t * 32 + quad * 8]);
                    sc[g] = __builtin_amdgcn_mfma_f32_16x16x32_bf16(qf[t], kf, sc[g], 0, 0, 0);
                }
            }

            const bool tail = (kt >= nkt - 2);
            #pragma unroll
            for (int r = 0; r < 4; r++) {
                const int qrow = qw + quad * 4 + r;
                #pragma unroll
                for (int g = 0; g < 4; g++) {
                    float p = exp2f(sc[g][r] * kS - kB);
                    if (tail && (k0 + g * 16 + c > qrow)) p = 0.0f;
                    l_part[r] += p;
                    psw[(quad * 4 + r) * 72 + g * 16 + c] = (bf16)p;
                }
            }
            asm volatile("s_waitcnt lgkmcnt(0)" ::: "memory");
            bf16x8 pf0 = *(const bf16x8*)(&psw[c * 72 + quad * 8]);
            bf16x8 pf1 = *(const bf16x8*)(&psw[c * 72 + 32 + quad * 8]);

            #pragma unroll
            for (int f = 0; f < 8; f++) {
                bf16x8 vf0 = *(const bf16x8*)(&Vs[(f * 16 + c) * 72 + quad * 8]);
                bf16x8 vf1 = *(const bf16x8*)(&Vs[(f * 16 + c) * 72 + 32 + quad * 8]);
                o_acc[f] = __builtin_amdgcn_mfma_f32_16x16x32_bf16(pf0, vf0, o_acc[f], 0, 0, 0);
                o_acc[f] = __builtin_amdgcn_mfma_f32_16x16x32_bf16(pf1, vf1, o_acc[f], 0, 0, 0);
            }
        }
        __syncthreads();
    }

    #pragma unroll
    for (int r = 0; r < 4; r++) {
        float l = l_part[r];
        #pragma unroll
        for (int msk = 8; msk; msk >>= 1) l += __shfl_xor(l, msk);
        const float inv = 1.0f / l;
        bf16* op = O + (size_t)(b * SEQ + qw + quad * 4 + r) * 2048 + h * HD;
        #pragma unroll
        for (int f = 0; f < 8; f++) op[f * 16 + c] = (bf16)(o_acc[f][r] * inv);
    }
}

// ---------------------------------------------------------------------------
extern "C" void kernel_launch(void* const* d_in, const int* in_sizes, int n_in,
                              void* d_out, int out_size, void* d_ws, size_t ws_size,
                              hipStream_t stream)
{
    const float* x   = (const float*)d_in[0];
    const float* pe  = (const float*)d_in[1];
    const float* qw  = (const float*)d_in[2];
    const float* kw  = (const float*)d_in[3];
    const float* vw  = (const float*)d_in[4];
    const float* ow  = (const float*)d_in[5];
    const float* qnw = (const float*)d_in[6];
    const float* knw = (const float*)d_in[7];
    float* out = (float*)d_out;

    bf16* qb = (bf16*)d_ws;          // [B][S][2048]   row-major (raw q)
    bf16* kb = qb + XN;              // [B][S][1024]   row-major
    bf16* vt = kb + KWN * 2;         // [B][1024][2048] V^T
    bf16* ab = vt + VWN * 2;         // [B][S][2048]   row-major
    bf16* cvt_base = ab + XN;

    const bool fit = ws_size >= (size_t)92274688;
    const int M = BATCH * SEQ;

    if (fit) {
        bf16* xb  = cvt_base;
        bf16* qwb = xb  + XN;
        bf16* owb = qwb + QWN + KWN + VWN;

        cvt_all<<<10240, 256, 0, stream>>>(xb, x, qw, kw, vw, ow);

        gemm256_qkv<<<dim3(16, 16), 512, 0, stream>>>(qb, xb, qwb);

        norm_rope_k<<<dim3(SEQ, NKV, BATCH), 128, 0, stream>>>(kb, pe, knw);
        fattn<<<dim3(SEQ / 128, BATCH, NH), 512, 0, stream>>>(ab, qb, kb, vt, pe, qnw);

        gemm128<1, 1, 0><<<dim3(32, 16), 256, 0, stream>>>(out, ab, owb, M, 2048, 2048);
    } else {
        gemm128<0, 0, 1><<<dim3(32, 16), 256, 0, stream>>>(qb, x, qw, M, 2048, 2048);
        gemm128<0, 0, 1><<<dim3(32,  8), 256, 0, stream>>>(kb, x, kw, M, 1024, 2048);
        gemm128<0, 0, 2><<<dim3(32,  8), 256, 0, stream>>>(vt, x, vw, M, 1024, 2048);

        norm_rope_k<<<dim3(SEQ, NKV, BATCH), 128, 0, stream>>>(kb, pe, knw);
        fattn<<<dim3(SEQ / 128, BATCH, NH), 512, 0, stream>>>(ab, qb, kb, vt, pe, qnw);

        gemm128<0, 0, 0><<<dim3(32, 16), 256, 0, stream>>>(out, ab, ow, M, 2048, 2048);
    }
}